// Round 1
// baseline (10143.562 us; speedup 1.0000x reference)
//
#include <hip/hip_runtime.h>
#include <math.h>

// VQ-VAE forward, fp32 direct baseline.
// Shapes: x[32,3,128,128]; H_DIM=256, e_dim=64, K=256 codes, BETA=0.25.

#define NB  32
#define CH  256
#define H0  128
#define H1  64
#define H2  32
#define ED  64
#define KCB 256

// ---------------- conv1: 3->256, k4 s2 p1, 128->64 ----------------
__global__ __launch_bounds__(256) void k_conv1(const float* __restrict__ x,
                                               const float* __restrict__ w,
                                               const float* __restrict__ b,
                                               float* __restrict__ y) {
    // grid: 32n * 256co * 16hb ; block 256 = 4ho x 64wo
    int bid = blockIdx.x;
    int hb = bid & 15;
    int co = (bid >> 4) & 255;
    int n  = bid >> 12;
    int wo = threadIdx.x & 63;
    int ho = (hb << 2) + (threadIdx.x >> 6);
    float acc = b[co];
    const float* wp = w + co * 48;          // [3][4][4]
    const float* xp = x + n * (3 * H0 * H0);
#pragma unroll
    for (int ci = 0; ci < 3; ++ci) {
#pragma unroll
        for (int kh = 0; kh < 4; ++kh) {
            int hi = ho * 2 - 1 + kh;
            if ((unsigned)hi < (unsigned)H0) {
#pragma unroll
                for (int kw = 0; kw < 4; ++kw) {
                    int wi = wo * 2 - 1 + kw;
                    if ((unsigned)wi < (unsigned)H0)
                        acc += xp[ci * (H0 * H0) + hi * H0 + wi] * wp[ci * 16 + kh * 4 + kw];
                }
            }
        }
    }
    y[((n * CH + co) * H1 + ho) * H1 + wo] = acc;
}

// ---------------- conv2: 256->256, k4 s2 p1, 64->32 ----------------
__global__ __launch_bounds__(256) void k_conv2(const float* __restrict__ x,
                                               const float* __restrict__ w,
                                               const float* __restrict__ b,
                                               float* __restrict__ y) {
    // grid: 32n * 32cb * 4ht ; block 256 = 8ho x 32wo ; 8 co per thread
    int bid = blockIdx.x;
    int ht = bid & 3;
    int cb = (bid >> 2) & 31;
    int n  = bid >> 7;
    int wo = threadIdx.x & 31;
    int ho = ht * 8 + (threadIdx.x >> 5);
    int co0 = cb * 8;
    float acc[8];
#pragma unroll
    for (int j = 0; j < 8; ++j) acc[j] = b[co0 + j];
    const float* xp = x + n * (CH * H1 * H1);
    for (int ci = 0; ci < CH; ++ci) {
        const float* xc = xp + ci * (H1 * H1);
        float xv[16];
#pragma unroll
        for (int kh = 0; kh < 4; ++kh) {
            int hi = ho * 2 - 1 + kh;
#pragma unroll
            for (int kw = 0; kw < 4; ++kw) {
                int wi = wo * 2 - 1 + kw;
                xv[kh * 4 + kw] = ((unsigned)hi < (unsigned)H1 && (unsigned)wi < (unsigned)H1)
                                      ? xc[hi * H1 + wi] : 0.f;
            }
        }
#pragma unroll
        for (int j = 0; j < 8; ++j) {
            const float* wp = w + ((co0 + j) * CH + ci) * 16;  // wave-uniform -> s_load
#pragma unroll
            for (int t = 0; t < 16; ++t) acc[j] += xv[t] * wp[t];
        }
    }
#pragma unroll
    for (int j = 0; j < 8; ++j)
        y[((n * CH + co0 + j) * H2 + ho) * H2 + wo] = acc[j];
}

// ---------------- conv3x3(relu(x)), pad 1, 32x32, no bias ----------------
__global__ __launch_bounds__(256) void k_res_conv3(const float* __restrict__ x,
                                                   const float* __restrict__ w,
                                                   float* __restrict__ y) {
    // grid: 32n * 32cb * 4ht ; block 256 = 8ho x 32wo ; 8 co per thread
    int bid = blockIdx.x;
    int ht = bid & 3;
    int cb = (bid >> 2) & 31;
    int n  = bid >> 7;
    int wo = threadIdx.x & 31;
    int ho = ht * 8 + (threadIdx.x >> 5);
    int co0 = cb * 8;
    float acc[8] = {0.f, 0.f, 0.f, 0.f, 0.f, 0.f, 0.f, 0.f};
    const float* xp = x + n * (CH * H2 * H2);
    for (int ci = 0; ci < CH; ++ci) {
        const float* xc = xp + ci * (H2 * H2);
        float xv[9];
#pragma unroll
        for (int kh = 0; kh < 3; ++kh) {
            int hi = ho - 1 + kh;
#pragma unroll
            for (int kw = 0; kw < 3; ++kw) {
                int wi = wo - 1 + kw;
                float v = ((unsigned)hi < (unsigned)H2 && (unsigned)wi < (unsigned)H2)
                              ? xc[hi * H2 + wi] : 0.f;
                xv[kh * 3 + kw] = v > 0.f ? v : 0.f;   // relu fused on load
            }
        }
#pragma unroll
        for (int j = 0; j < 8; ++j) {
            const float* wp = w + ((co0 + j) * CH + ci) * 9;   // wave-uniform
#pragma unroll
            for (int t = 0; t < 9; ++t) acc[j] += xv[t] * wp[t];
        }
    }
#pragma unroll
    for (int j = 0; j < 8; ++j)
        y[((n * CH + co0 + j) * H2 + ho) * H2 + wo] = acc[j];
}

// ---------------- conv1x1(relu(t)) + res ----------------
__global__ __launch_bounds__(256) void k_res_conv1(const float* __restrict__ t,
                                                   const float* __restrict__ w,
                                                   const float* __restrict__ res,
                                                   float* __restrict__ y) {
    // grid: 32n * 32cb * 4st ; block 256 over spatial ; 8 co per thread
    int bid = blockIdx.x;
    int st = bid & 3;
    int cb = (bid >> 2) & 31;
    int n  = bid >> 7;
    int s  = st * 256 + threadIdx.x;      // spatial index in [0,1024)
    int co0 = cb * 8;
    float acc[8] = {0.f, 0.f, 0.f, 0.f, 0.f, 0.f, 0.f, 0.f};
    const float* tp = t + n * (CH * 1024) + s;
    for (int ci = 0; ci < CH; ++ci) {
        float v = tp[ci * 1024];
        v = v > 0.f ? v : 0.f;
#pragma unroll
        for (int j = 0; j < 8; ++j) acc[j] += v * w[(co0 + j) * CH + ci];
    }
#pragma unroll
    for (int j = 0; j < 8; ++j) {
        int o = n * (CH * 1024) + (co0 + j) * 1024 + s;
        y[o] = acc[j] + res[o];
    }
}

// ---------------- VQ: argmin over 256 codes, 64-dim rows ----------------
__global__ __launch_bounds__(256) void k_vq(const float* __restrict__ z,
                                            const float* __restrict__ cb,
                                            float* __restrict__ vq,
                                            float* __restrict__ loss) {
    // rows mapped t = ((g*32+n)*32+h)*32+w  -> coalesced over w
    int t = blockIdx.x * 256 + threadIdx.x;
    int w = t & 31;
    int h = (t >> 5) & 31;
    int n = (t >> 10) & 31;
    int g = t >> 15;
    const float* zp = z + ((n * CH + g * ED) * H2 + h) * H2 + w;  // stride 1024/j
    float zv[ED];
#pragma unroll
    for (int j = 0; j < ED; ++j) zv[j] = zp[j * 1024];
    float best = 3.4e38f;
    int bi = 0;
    for (int k = 0; k < KCB; ++k) {
        const float* e = cb + k * ED;   // wave-uniform -> s_load
        float d = 0.f;
#pragma unroll
        for (int j = 0; j < ED; ++j) {
            float df = zv[j] - e[j];
            d += df * df;
        }
        if (d < best) { best = d; bi = k; }   // strict < keeps first min (np semantics)
    }
    const float* e = cb + bi * ED;
    float* vp = vq + ((n * CH + g * ED) * H2 + h) * H2 + w;
#pragma unroll
    for (int j = 0; j < ED; ++j) vp[j * 1024] = e[j];

    // loss: best == sum_j (z-e)^2 for this row; total mean over 32*32*32*256 elems, x1.25
    float l = best;
#pragma unroll
    for (int off = 32; off > 0; off >>= 1) l += __shfl_down(l, off);
    __shared__ float ls[4];
    if ((threadIdx.x & 63) == 0) ls[threadIdx.x >> 6] = l;
    __syncthreads();
    if (threadIdx.x == 0) {
        float ssum = ls[0] + ls[1] + ls[2] + ls[3];
        atomicAdd(loss, ssum * (1.25f / 8388608.f));
    }
}

// ---------------- deconv1: 256->256, k4 s2 p1, 32->64 ----------------
__global__ __launch_bounds__(256) void k_deconv1(const float* __restrict__ x,
                                                 const float* __restrict__ w,
                                                 const float* __restrict__ b,
                                                 float* __restrict__ y) {
    // parity-class blocks: grid 32n * 32cb * 4cls * 4oyt ; block 256 = 8oy x 32ox
    int bid = blockIdx.x;
    int oyt = bid & 3;
    int cls = (bid >> 2) & 3;
    int cbk = (bid >> 4) & 31;
    int n   = bid >> 9;
    int px = cls & 1, py = cls >> 1;
    int ox = threadIdx.x & 31;
    int oy = oyt * 8 + (threadIdx.x >> 5);
    int ho = oy * 2 + py, wo = ox * 2 + px;
    int co0 = cbk * 8;
    int kh0 = (py + 1) & 1;   // valid kh parity
    int kw0 = (px + 1) & 1;
    int hiA = (ho + 1 - kh0) >> 1, hiB = hiA - 1;
    int wiA = (wo + 1 - kw0) >> 1, wiB = wiA - 1;
    bool vA = (unsigned)hiA < (unsigned)H2, vB = (unsigned)hiB < (unsigned)H2;
    bool uA = (unsigned)wiA < (unsigned)H2, uB = (unsigned)wiB < (unsigned)H2;
    float acc[8];
#pragma unroll
    for (int j = 0; j < 8; ++j) acc[j] = b[co0 + j];
    const float* xp = x + n * (CH * H2 * H2);
    for (int ci = 0; ci < CH; ++ci) {
        const float* xc = xp + ci * (H2 * H2);
        float xAA = (vA && uA) ? xc[hiA * H2 + wiA] : 0.f;
        float xAB = (vA && uB) ? xc[hiA * H2 + wiB] : 0.f;
        float xBA = (vB && uA) ? xc[hiB * H2 + wiA] : 0.f;
        float xBB = (vB && uB) ? xc[hiB * H2 + wiB] : 0.f;
#pragma unroll
        for (int j = 0; j < 8; ++j) {
            const float* wp = w + (ci * CH + co0 + j) * 16;  // [in][out][4][4], uniform
            acc[j] += xAA * wp[kh0 * 4 + kw0]
                    + xAB * wp[kh0 * 4 + kw0 + 2]
                    + xBA * wp[(kh0 + 2) * 4 + kw0]
                    + xBB * wp[(kh0 + 2) * 4 + kw0 + 2];
        }
    }
#pragma unroll
    for (int j = 0; j < 8; ++j)
        y[((n * CH + co0 + j) * H1 + ho) * H1 + wo] = acc[j];
}

// ---------------- deconv2: 256->3, k4 s2 p1, 64->128, + tanh ----------------
__global__ __launch_bounds__(256) void k_deconv2(const float* __restrict__ x,
                                                 const float* __restrict__ w,
                                                 const float* __restrict__ b,
                                                 float* __restrict__ y) {
    // grid: 32n * 4cls * 16oyt ; block 256 = 4oy x 64ox ; 3 co per thread
    int bid = blockIdx.x;
    int oyt = bid & 15;
    int cls = (bid >> 4) & 3;
    int n   = bid >> 6;
    int px = cls & 1, py = cls >> 1;
    int ox = threadIdx.x & 63;
    int oy = oyt * 4 + (threadIdx.x >> 6);
    int ho = oy * 2 + py, wo = ox * 2 + px;
    int kh0 = (py + 1) & 1, kw0 = (px + 1) & 1;
    int hiA = (ho + 1 - kh0) >> 1, hiB = hiA - 1;
    int wiA = (wo + 1 - kw0) >> 1, wiB = wiA - 1;
    bool vA = (unsigned)hiA < (unsigned)H1, vB = (unsigned)hiB < (unsigned)H1;
    bool uA = (unsigned)wiA < (unsigned)H1, uB = (unsigned)wiB < (unsigned)H1;
    float acc[3] = {b[0], b[1], b[2]};
    const float* xp = x + n * (CH * H1 * H1);
    for (int ci = 0; ci < CH; ++ci) {
        const float* xc = xp + ci * (H1 * H1);
        float xAA = (vA && uA) ? xc[hiA * H1 + wiA] : 0.f;
        float xAB = (vA && uB) ? xc[hiA * H1 + wiB] : 0.f;
        float xBA = (vB && uA) ? xc[hiB * H1 + wiA] : 0.f;
        float xBB = (vB && uB) ? xc[hiB * H1 + wiB] : 0.f;
#pragma unroll
        for (int j = 0; j < 3; ++j) {
            const float* wp = w + (ci * 3 + j) * 16;   // [in][3][4][4], uniform
            acc[j] += xAA * wp[kh0 * 4 + kw0]
                    + xAB * wp[kh0 * 4 + kw0 + 2]
                    + xBA * wp[(kh0 + 2) * 4 + kw0]
                    + xBB * wp[(kh0 + 2) * 4 + kw0 + 2];
        }
    }
#pragma unroll
    for (int j = 0; j < 3; ++j)
        y[((n * 3 + j) * H0 + ho) * H0 + wo] = tanhf(acc[j]);
}

extern "C" void kernel_launch(void* const* d_in, const int* in_sizes, int n_in,
                              void* d_out, int out_size, void* d_ws, size_t ws_size,
                              hipStream_t stream) {
    const float* x        = (const float*)d_in[0];
    const float* enc_w1   = (const float*)d_in[1];
    const float* enc_b1   = (const float*)d_in[2];
    const float* enc_w2   = (const float*)d_in[3];
    const float* enc_b2   = (const float*)d_in[4];
    const float* er1_w3   = (const float*)d_in[5];
    const float* er1_w1   = (const float*)d_in[6];
    const float* er2_w3   = (const float*)d_in[7];
    const float* er2_w1   = (const float*)d_in[8];
    const float* codebook = (const float*)d_in[9];
    const float* dr1_w3   = (const float*)d_in[10];
    const float* dr1_w1   = (const float*)d_in[11];
    const float* dr2_w3   = (const float*)d_in[12];
    const float* dr2_w1   = (const float*)d_in[13];
    const float* dt1_w    = (const float*)d_in[14];
    const float* dt1_b    = (const float*)d_in[15];
    const float* dt2_w    = (const float*)d_in[16];
    const float* dt2_b    = (const float*)d_in[17];

    float* out   = (float*)d_out;
    float* recon = out;                       // 32*3*128*128 = 1572864
    float* loss  = out + 1572864;             // scalar

    float* ws = (float*)d_ws;
    float* A  = ws;                // 33,554,432 floats (z1, later deconv1 out)
    float* B  = ws + 33554432;     // 8,388,608 floats
    float* Cb = ws + 41943040;     // 8,388,608 floats
    float* D  = ws + 50331648;     // 8,388,608 floats
    // total ws use: 58,720,256 floats = 224 MiB

    hipMemsetAsync(loss, 0, sizeof(float), stream);

    // encoder
    k_conv1<<<131072, 256, 0, stream>>>(x, enc_w1, enc_b1, A);      // x -> z1 (A)
    k_conv2<<<4096, 256, 0, stream>>>(A, enc_w2, enc_b2, B);        // z1 -> z2 (B)
    // er1: D = conv1x1(relu(conv3(relu(B)))) + B
    k_res_conv3<<<4096, 256, 0, stream>>>(B, er1_w3, Cb);
    k_res_conv1<<<4096, 256, 0, stream>>>(Cb, er1_w1, B, D);
    // er2: B = res(D)   -> z4
    k_res_conv3<<<4096, 256, 0, stream>>>(D, er2_w3, Cb);
    k_res_conv1<<<4096, 256, 0, stream>>>(Cb, er2_w1, D, B);
    // VQ: B -> vq (D), loss
    k_vq<<<512, 256, 0, stream>>>(B, codebook, D, loss);
    // dr1: B = res(D)
    k_res_conv3<<<4096, 256, 0, stream>>>(D, dr1_w3, Cb);
    k_res_conv1<<<4096, 256, 0, stream>>>(Cb, dr1_w1, D, B);
    // dr2: D = res(B)
    k_res_conv3<<<4096, 256, 0, stream>>>(B, dr2_w3, Cb);
    k_res_conv1<<<4096, 256, 0, stream>>>(Cb, dr2_w1, B, D);
    // decoder deconvs
    k_deconv1<<<16384, 256, 0, stream>>>(D, dt1_w, dt1_b, A);       // D -> A [32,256,64,64]
    k_deconv2<<<2048, 256, 0, stream>>>(A, dt2_w, dt2_b, recon);    // A -> recon, tanh
}

// Round 2
// 1705.391 us; speedup vs baseline: 5.9479x; 5.9479x over previous
//
#include <hip/hip_runtime.h>
#include <math.h>

// VQ-VAE forward. Heavy convs (Cin=Cout=256) via bf16 MFMA implicit GEMM.
// Activations: bf16 NHWC (relu fused at write) for MFMA consumers; fp32 NCHW
// kept for residual adds and VQ. Weights repacked per-launch into exact
// A-fragment order (bf16).

typedef unsigned short ushort;
typedef short bf16x8 __attribute__((ext_vector_type(8)));
typedef float f32x4 __attribute__((ext_vector_type(4)));

__device__ __forceinline__ ushort f2bf(float f) {
    unsigned u = __builtin_bit_cast(unsigned, f);
    unsigned r = (u + 0x7fffu + ((u >> 16) & 1u)) >> 16;
    return (ushort)r;
}
__device__ __forceinline__ float bfl(unsigned u) {            // low half
    return __builtin_bit_cast(float, u << 16);
}
__device__ __forceinline__ float bfh(unsigned u) {            // high half
    return __builtin_bit_cast(float, u & 0xffff0000u);
}

// ======================= weight packing =======================
// Packed layout (per layer): [cls][tap][cb(8)][co(256)][k(32)] bf16,
// where k = ci within ci-block, matching A-fragment lane order.

__global__ void k_pack_c3(const float* __restrict__ w, ushort* __restrict__ o) {
    int i = blockIdx.x * 256 + threadIdx.x;           // 9*8*256*32 = 589824
    int kk = i & 31, co = (i >> 5) & 255, cb = (i >> 13) & 7, t = i >> 16;
    int ci = cb * 32 + kk, kh = t / 3, kw = t % 3;
    o[i] = f2bf(w[((co * 256 + ci) * 3 + kh) * 3 + kw]);
}

__global__ void k_pack_c1x1(const float* __restrict__ w, ushort* __restrict__ o) {
    int i = blockIdx.x * 256 + threadIdx.x;           // 8*256*32 = 65536
    int kk = i & 31, co = (i >> 5) & 255, cb = (i >> 13) & 7;
    int ci = cb * 32 + kk;
    o[i] = f2bf(w[co * 256 + ci]);
}

__global__ void k_pack_c2(const float* __restrict__ w, ushort* __restrict__ o) {
    int i = blockIdx.x * 256 + threadIdx.x;           // 4*4*8*256*32 = 1048576
    int kk = i & 31, co = (i >> 5) & 255, cb = (i >> 13) & 7;
    int t = (i >> 16) & 3, cls = i >> 18;
    int ph = cls >> 1, pw = cls & 1, a = t >> 1, b = t & 1;
    int kh = ph ? 2 * a : 2 * a + 1;
    int kw = pw ? 2 * b : 2 * b + 1;
    int ci = cb * 32 + kk;
    o[i] = f2bf(w[((co * 256 + ci) * 4 + kh) * 4 + kw]);
}

__global__ void k_pack_dc1(const float* __restrict__ w, ushort* __restrict__ o) {
    int i = blockIdx.x * 256 + threadIdx.x;           // 1048576, src [ci][co][4][4]
    int kk = i & 31, co = (i >> 5) & 255, cb = (i >> 13) & 7;
    int t = (i >> 16) & 3, cls = i >> 18;
    int py = cls >> 1, px = cls & 1, a = t >> 1, b = t & 1;
    int kh0 = (py + 1) & 1, kw0 = (px + 1) & 1;
    int ci = cb * 32 + kk;
    o[i] = f2bf(w[((ci * 256 + co) * 4 + kh0 + 2 * a) * 4 + kw0 + 2 * b]);
}

__global__ void k_pack_c1f(const float* __restrict__ w, float* __restrict__ o) {
    int i = blockIdx.x * 256 + threadIdx.x;           // 48*256 = 12288
    int co = i & 255, k = i >> 8;
    int ci = k >> 4, kh = (k >> 2) & 3, kw = k & 3;
    o[k * 256 + co] = w[((co * 3 + ci) * 4 + kh) * 4 + kw];
}

__global__ void k_pack_dc2(const float* __restrict__ w, float* __restrict__ o) {
    int i = blockIdx.x * 256 + threadIdx.x;           // 4cls*256ci*4tap*3co = 12288
    if (i >= 12288) return;
    int co = i % 3, t = (i / 3) & 3, ci = (i / 12) & 255, cls = i / 3072;
    int py = cls >> 1, px = cls & 1, a = t >> 1, b = t & 1;
    int kh0 = (py + 1) & 1, kw0 = (px + 1) & 1;
    o[((cls * 256 + ci) * 4 + t) * 3 + co] =
        w[((ci * 3 + co) * 4 + kh0 + 2 * a) * 4 + kw0 + 2 * b];
}

// ======================= conv1: 3->256 k4 s2, 128->64, direct fp32 =======================
__global__ __launch_bounds__(256) void k_conv1n(const float* __restrict__ x,
                                                const float* __restrict__ wt,   // [48][256] f32
                                                const float* __restrict__ bias,
                                                ushort* __restrict__ o) {       // NHWC64 bf16
    int b = blockIdx.x;                  // 32n * 64h
    int h = b & 63, n = b >> 6;
    int co = threadIdx.x;
    float wr[48];
#pragma unroll
    for (int k = 0; k < 48; ++k) wr[k] = wt[k * 256 + co];
    const float* xp = x + (long)n * 3 * 128 * 128;
    float bco = bias[co];
    for (int w = 0; w < 64; ++w) {
        float acc = bco;
#pragma unroll
        for (int ci = 0; ci < 3; ++ci)
#pragma unroll
            for (int kh = 0; kh < 4; ++kh) {
                int hi = 2 * h - 1 + kh;
                if ((unsigned)hi < 128u) {
                    const float* row = xp + (ci * 128 + hi) * 128;
#pragma unroll
                    for (int kw = 0; kw < 4; ++kw) {
                        int wi = 2 * w - 1 + kw;
                        if ((unsigned)wi < 128u) acc += row[wi] * wr[(ci * 4 + kh) * 4 + kw];
                    }
                }
            }
        o[(((long)n * 64 + h) * 64 + w) * 256 + co] = f2bf(acc);
    }
}

// ======================= unified MFMA conv =======================
// MODE 0: 3x3 pad1 (9 taps), in 32x32 NHWC
// MODE 1: 1x1
// MODE 2: conv2 4x4 s2 (4 phases x 4 taps), in 64x64 NHWC
// MODE 3: deconv1 per-parity (4 taps), in 32x32 NHWC, out 64x64 NHWC
// Block: 128 threads = 2 waves. Block tile 128co x 128m. Wave tile 64co x 128m.
#define SX_W   56
#define SX_ROW (34 * SX_W)

template <int MODE, bool HAS_BIAS, bool ADD_RES, bool WRITE_F32, bool WRITE_BF16, bool RELU_BF16>
__global__ __launch_bounds__(128, 2) void k_mconv(const ushort* __restrict__ xin,
                                                  const ushort* __restrict__ wpk,
                                                  const float* __restrict__ bias,
                                                  const float* __restrict__ res,
                                                  float* __restrict__ of32,
                                                  ushort* __restrict__ obf) {
    constexpr int NT = (MODE == 0) ? 9 : ((MODE == 1) ? 1 : 4);
    constexpr int NOUT = (MODE == 2) ? 32 : 8;

    __shared__ __align__(16) ushort sX[6 * SX_ROW];   // 6 rows x 34 wpad x (32ci+24pad)

    int tid = threadIdx.x;
    int lane = tid & 63, wv = tid >> 6;
    int q = lane >> 4, l15 = lane & 15;
    int b = blockIdx.x;
    int mblk = b & 7, slab = (b >> 3) & 1;
    int cls = (MODE == 3) ? ((b >> 4) & 3) : 0;
    int n = (MODE == 3) ? (b >> 6) : (b >> 4);
    int h0 = mblk * 4;

    // zero the w-pad columns (c=0 and c=33), all 6 rows, ci 0..31
    for (int i = tid; i < 384; i += 128) {
        int r = i >> 6, rem = i & 63, cc = rem >> 5, ci = rem & 31;
        sX[(r * 34 + (cc ? 33 : 0)) * SX_W + ci] = 0;
    }

    // staging thread map: 32 w-positions x 4 ci-octets
    int ciq = (tid & 3) * 8;
    int wst = tid >> 2;

    // B-fragment LDS bases (tap offset added later)
    int bbase[8];
#pragma unroll
    for (int bt = 0; bt < 8; ++bt) {
        int ro = bt >> 1, col = (bt & 1) * 16 + l15;
        bbase[bt] = ((ro + 1) * 34 + col + 1) * SX_W + q * 8;
    }

    f32x4 acc[4][8];
#pragma unroll
    for (int at = 0; at < 4; ++at)
#pragma unroll
        for (int bt = 0; bt < 8; ++bt) acc[at][bt] = 0.f;

    for (int it = 0; it < NOUT; ++it) {
        int cb = (MODE == 2) ? (it >> 2) : it;
        int ph = (MODE == 2) ? (it & 3) : 0;
        int ph_h = ph >> 1, ph_w = ph & 1;

        // ---- stage X tile (rows h0-1 .. h0+4), zero-filled outside image ----
#pragma unroll
        for (int r = 0; r < 6; ++r) {
            if (MODE == 1 && (r == 0 || r == 5)) continue;   // 1x1 uses rows 1..4 only
            int hh = h0 + r - 1;
            bool valid = (unsigned)hh < 32u;
            long off;
            if (MODE == 2)
                off = (((long)n * 64 + 2 * hh + ph_h) * 64 + (2 * wst + ph_w)) * 256 + cb * 32 + ciq;
            else
                off = (((long)n * 32 + hh) * 32 + wst) * 256 + cb * 32 + ciq;
            uint4 v;
            if (valid) v = *(const uint4*)(xin + off);
            else { v.x = 0; v.y = 0; v.z = 0; v.w = 0; }
            *(uint4*)&sX[(r * 34 + wst + 1) * SX_W + ciq] = v;
        }
        __syncthreads();

        for (int t = 0; t < NT; ++t) {
            int dy, dx;
            if (MODE == 0) { dy = t / 3 - 1; dx = t % 3 - 1; }
            else if (MODE == 1) { dy = 0; dx = 0; }
            else if (MODE == 2) { dy = (t >> 1) - ph_h; dx = (t & 1) - ph_w; }
            else { dy = (cls >> 1) - (t >> 1); dx = (cls & 1) - (t & 1); }

            int clsi = (MODE == 2) ? ph : cls;
            const ushort* wp = wpk +
                ((((long)(clsi * NT + t)) * 8 + cb) * 256 + slab * 128 + wv * 64 + l15) * 32 + q * 8;
            bf16x8 af[4];
#pragma unroll
            for (int at = 0; at < 4; ++at) af[at] = *(const bf16x8*)(wp + at * 512);

            int doff = (dy * 34 + dx) * SX_W;
            bf16x8 bfr[8];
#pragma unroll
            for (int bt = 0; bt < 8; ++bt) bfr[bt] = *(const bf16x8*)&sX[bbase[bt] + doff];

#pragma unroll
            for (int at = 0; at < 4; ++at)
#pragma unroll
                for (int bt = 0; bt < 8; ++bt)
                    acc[at][bt] = __builtin_amdgcn_mfma_f32_16x16x32_bf16(af[at], bfr[bt],
                                                                          acc[at][bt], 0, 0, 0);
        }
        __syncthreads();
    }

    // ---- epilogue ----
    int co_base = slab * 128 + wv * 64;
#pragma unroll
    for (int at = 0; at < 4; ++at) {
        int co_t = co_base + at * 16 + q * 4;
        float bv[4] = {0.f, 0.f, 0.f, 0.f};
        if (HAS_BIAS) {
            float4 b4 = *(const float4*)(bias + co_t);
            bv[0] = b4.x; bv[1] = b4.y; bv[2] = b4.z; bv[3] = b4.w;
        }
#pragma unroll
        for (int bt = 0; bt < 8; ++bt) {
            int m = mblk * 128 + bt * 16 + l15;     // position within 32x32 image
            float v[4];
#pragma unroll
            for (int r = 0; r < 4; ++r) v[r] = acc[at][bt][r] + bv[r];
            if (ADD_RES) {
#pragma unroll
                for (int r = 0; r < 4; ++r)
                    v[r] += res[((long)(n * 256 + co_t + r)) * 1024 + m];
            }
            if (WRITE_F32) {
#pragma unroll
                for (int r = 0; r < 4; ++r)
                    of32[((long)(n * 256 + co_t + r)) * 1024 + m] = v[r];
            }
            if (WRITE_BF16) {
                unsigned p0, p1;
                {
                    float z0 = RELU_BF16 ? fmaxf(v[0], 0.f) : v[0];
                    float z1 = RELU_BF16 ? fmaxf(v[1], 0.f) : v[1];
                    float z2 = RELU_BF16 ? fmaxf(v[2], 0.f) : v[2];
                    float z3 = RELU_BF16 ? fmaxf(v[3], 0.f) : v[3];
                    p0 = (unsigned)f2bf(z0) | ((unsigned)f2bf(z1) << 16);
                    p1 = (unsigned)f2bf(z2) | ((unsigned)f2bf(z3) << 16);
                }
                long oaddr;
                if (MODE == 3) {
                    int oy = m >> 5, ox = m & 31;
                    int py = cls >> 1, px = cls & 1;
                    oaddr = (((long)n * 64 + 2 * oy + py) * 64 + 2 * ox + px) * 256 + co_t;
                } else {
                    oaddr = ((long)n * 1024 + m) * 256 + co_t;
                }
                uint2 pk; pk.x = p0; pk.y = p1;
                *(uint2*)(obf + oaddr) = pk;
            }
        }
    }
}

// ======================= VQ =======================
__global__ __launch_bounds__(256) void k_vq(const float* __restrict__ z,
                                            const float* __restrict__ cbk,
                                            float* __restrict__ vqf,     // fp32 NCHW
                                            ushort* __restrict__ vqb,    // bf16 NHWC, relu
                                            float* __restrict__ loss) {
    int t = blockIdx.x * 256 + threadIdx.x;
    int w = t & 31, h = (t >> 5) & 31, n = (t >> 10) & 31, g = t >> 15;
    const float* zp = z + ((n * 256 + g * 64) * 32 + h) * 32 + w;
    float zv[64];
#pragma unroll
    for (int j = 0; j < 64; ++j) zv[j] = zp[j * 1024];
    float best = 3.4e38f;
    int bi = 0;
    for (int k = 0; k < 256; ++k) {
        const float* e = cbk + k * 64;
        float d = 0.f;
#pragma unroll
        for (int j = 0; j < 64; ++j) {
            float df = zv[j] - e[j];
            d += df * df;
        }
        if (d < best) { best = d; bi = k; }
    }
    const float* e = cbk + bi * 64;
    float* vp = vqf + ((n * 256 + g * 64) * 32 + h) * 32 + w;
    ushort* bp = vqb + (((long)n * 32 + h) * 32 + w) * 256 + g * 64;
#pragma unroll
    for (int j = 0; j < 64; ++j) vp[j * 1024] = e[j];
#pragma unroll
    for (int j = 0; j < 64; j += 4) {
        uint2 pk;
        pk.x = (unsigned)f2bf(fmaxf(e[j], 0.f)) | ((unsigned)f2bf(fmaxf(e[j + 1], 0.f)) << 16);
        pk.y = (unsigned)f2bf(fmaxf(e[j + 2], 0.f)) | ((unsigned)f2bf(fmaxf(e[j + 3], 0.f)) << 16);
        *(uint2*)(bp + j) = pk;
    }
    float l = best;
#pragma unroll
    for (int off = 32; off > 0; off >>= 1) l += __shfl_down(l, off);
    __shared__ float ls[4];
    if ((threadIdx.x & 63) == 0) ls[threadIdx.x >> 6] = l;
    __syncthreads();
    if (threadIdx.x == 0)
        atomicAdd(loss, (ls[0] + ls[1] + ls[2] + ls[3]) * (1.25f / 8388608.f));
}

// ======================= deconv2: 256->3, 64->128, tanh =======================
__global__ __launch_bounds__(256) void k_deconv2n(const ushort* __restrict__ xin,  // NHWC64 bf16
                                                  const float* __restrict__ w2,    // [cls][256][4tap][3co]
                                                  const float* __restrict__ bias,
                                                  float* __restrict__ o) {
    int b = blockIdx.x;                       // 32n * 4cls * 16tl
    int tl = b & 15, cls = (b >> 4) & 3, n = b >> 6;
    int px = cls & 1, py = cls >> 1;
    int tid = threadIdx.x;
    int ox = tid & 63, oy = tl * 4 + (tid >> 6);
    int ho = 2 * oy + py, wo = 2 * ox + px;
    int hiA = py ? oy + 1 : oy, hiB = hiA - 1;
    int wiA = px ? ox + 1 : ox, wiB = wiA - 1;
    bool vA = (unsigned)hiA < 64u, vB = (unsigned)hiB < 64u;
    bool uA = (unsigned)wiA < 64u, uB = (unsigned)wiB < 64u;
    const ushort* base = xin + (long)n * 64 * 64 * 256;
    const ushort* pAA = base + ((long)(hiA * 64 + wiA)) * 256;
    const ushort* pAB = base + ((long)(hiA * 64 + wiB)) * 256;
    const ushort* pBA = base + ((long)(hiB * 64 + wiA)) * 256;
    const ushort* pBB = base + ((long)(hiB * 64 + wiB)) * 256;
    bool mAA = vA && uA, mAB = vA && uB, mBA = vB && uA, mBB = vB && uB;
    float a0 = bias[0], a1 = bias[1], a2 = bias[2];
    const float* wrow0 = w2 + (long)cls * 256 * 12;
    for (int c = 0; c < 32; ++c) {
        uint4 z; z.x = z.y = z.z = z.w = 0;
        uint4 qa = mAA ? *(const uint4*)(pAA + c * 8) : z;
        uint4 qb = mAB ? *(const uint4*)(pAB + c * 8) : z;
        uint4 qc = mBA ? *(const uint4*)(pBA + c * 8) : z;
        uint4 qd = mBB ? *(const uint4*)(pBB + c * 8) : z;
        const float* wr = wrow0 + c * 96;
        const unsigned* ua = (const unsigned*)&qa;
        const unsigned* ub = (const unsigned*)&qb;
        const unsigned* uc = (const unsigned*)&qc;
        const unsigned* ud = (const unsigned*)&qd;
#pragma unroll
        for (int d = 0; d < 4; ++d) {
#pragma unroll
            for (int s = 0; s < 2; ++s) {
                float xAA = s ? bfh(ua[d]) : bfl(ua[d]);
                float xAB = s ? bfh(ub[d]) : bfl(ub[d]);
                float xBA = s ? bfh(uc[d]) : bfl(uc[d]);
                float xBB = s ? bfh(ud[d]) : bfl(ud[d]);
                const float* wp = wr + (d * 2 + s) * 12;
                a0 += xAA * wp[0] + xAB * wp[3] + xBA * wp[6] + xBB * wp[9];
                a1 += xAA * wp[1] + xAB * wp[4] + xBA * wp[7] + xBB * wp[10];
                a2 += xAA * wp[2] + xAB * wp[5] + xBA * wp[8] + xBB * wp[11];
            }
        }
    }
    long ob = ((long)(n * 3) * 128 + ho) * 128 + wo;
    o[ob] = tanhf(a0);
    o[ob + 16384] = tanhf(a1);
    o[ob + 32768] = tanhf(a2);
}

// ======================= launcher =======================
extern "C" void kernel_launch(void* const* d_in, const int* in_sizes, int n_in,
                              void* d_out, int out_size, void* d_ws, size_t ws_size,
                              hipStream_t stream) {
    (void)in_sizes; (void)n_in; (void)out_size; (void)ws_size;
    const float* x        = (const float*)d_in[0];
    const float* enc_w1   = (const float*)d_in[1];
    const float* enc_b1   = (const float*)d_in[2];
    const float* enc_w2   = (const float*)d_in[3];
    const float* enc_b2   = (const float*)d_in[4];
    const float* er1_w3   = (const float*)d_in[5];
    const float* er1_w1   = (const float*)d_in[6];
    const float* er2_w3   = (const float*)d_in[7];
    const float* er2_w1   = (const float*)d_in[8];
    const float* codebook = (const float*)d_in[9];
    const float* dr1_w3   = (const float*)d_in[10];
    const float* dr1_w1   = (const float*)d_in[11];
    const float* dr2_w3   = (const float*)d_in[12];
    const float* dr2_w1   = (const float*)d_in[13];
    const float* dt1_w    = (const float*)d_in[14];
    const float* dt1_b    = (const float*)d_in[15];
    const float* dt2_w    = (const float*)d_in[16];
    const float* dt2_b    = (const float*)d_in[17];

    float* recon = (float*)d_out;
    float* loss  = recon + 1572864;

    char* ws = (char*)d_ws;
    size_t off = 0;
    auto alloc = [&](size_t bytes) { char* p = ws + off; off += (bytes + 255) & ~(size_t)255; return p; };
    ushort* N64  = (ushort*)alloc(67108864);   // [32,64,64,256] bf16 (conv1 out, later deconv1 out)
    float*  F0   = (float*)alloc(33554432);    // fp32 NCHW rotating
    float*  F1   = (float*)alloc(33554432);
    ushort* B0   = (ushort*)alloc(16777216);   // bf16 NHWC 32x32 rotating
    ushort* B1   = (ushort*)alloc(16777216);
    ushort* B2   = (ushort*)alloc(16777216);
    ushort* wpk_c2   = (ushort*)alloc(2097152);
    ushort* wpk_dc1  = (ushort*)alloc(2097152);
    ushort* wpk_er13 = (ushort*)alloc(1179648);
    ushort* wpk_er23 = (ushort*)alloc(1179648);
    ushort* wpk_dr13 = (ushort*)alloc(1179648);
    ushort* wpk_dr23 = (ushort*)alloc(1179648);
    ushort* wpk_er11 = (ushort*)alloc(131072);
    ushort* wpk_er21 = (ushort*)alloc(131072);
    ushort* wpk_dr11 = (ushort*)alloc(131072);
    ushort* wpk_dr21 = (ushort*)alloc(131072);
    float*  wt_c1    = (float*)alloc(49152);
    float*  w2pk     = (float*)alloc(49152);

    hipMemsetAsync(loss, 0, sizeof(float), stream);

    // weight packing
    k_pack_c1f<<<48, 256, 0, stream>>>(enc_w1, wt_c1);
    k_pack_c2<<<4096, 256, 0, stream>>>(enc_w2, wpk_c2);
    k_pack_c3<<<2304, 256, 0, stream>>>(er1_w3, wpk_er13);
    k_pack_c3<<<2304, 256, 0, stream>>>(er2_w3, wpk_er23);
    k_pack_c3<<<2304, 256, 0, stream>>>(dr1_w3, wpk_dr13);
    k_pack_c3<<<2304, 256, 0, stream>>>(dr2_w3, wpk_dr23);
    k_pack_c1x1<<<256, 256, 0, stream>>>(er1_w1, wpk_er11);
    k_pack_c1x1<<<256, 256, 0, stream>>>(er2_w1, wpk_er21);
    k_pack_c1x1<<<256, 256, 0, stream>>>(dr1_w1, wpk_dr11);
    k_pack_c1x1<<<256, 256, 0, stream>>>(dr2_w1, wpk_dr21);
    k_pack_dc1<<<4096, 256, 0, stream>>>(dt1_w, wpk_dc1);
    k_pack_dc2<<<48, 256, 0, stream>>>(dt2_w, w2pk);

    // encoder
    k_conv1n<<<2048, 256, 0, stream>>>(x, wt_c1, enc_b1, N64);
    // conv2: N64 -> F0 (fp32) + B0 (bf16 relu)
    k_mconv<2, true, false, true, true, true><<<512, 128, 0, stream>>>(N64, wpk_c2, enc_b2, nullptr, F0, B0);
    // er1
    k_mconv<0, false, false, false, true, true><<<512, 128, 0, stream>>>(B0, wpk_er13, nullptr, nullptr, nullptr, B1);
    k_mconv<1, false, true, true, true, true><<<512, 128, 0, stream>>>(B1, wpk_er11, nullptr, F0, F1, B0);
    // er2
    k_mconv<0, false, false, false, true, true><<<512, 128, 0, stream>>>(B0, wpk_er23, nullptr, nullptr, nullptr, B1);
    k_mconv<1, false, true, true, false, false><<<512, 128, 0, stream>>>(B1, wpk_er21, nullptr, F1, F0, nullptr);
    // VQ: F0 -> F1 (fp32) + B0 (bf16 relu) + loss
    k_vq<<<512, 256, 0, stream>>>(F0, codebook, F1, B0, loss);
    // dr1
    k_mconv<0, false, false, false, true, true><<<512, 128, 0, stream>>>(B0, wpk_dr13, nullptr, nullptr, nullptr, B1);
    k_mconv<1, false, true, true, true, true><<<512, 128, 0, stream>>>(B1, wpk_dr11, nullptr, F1, F0, B0);
    // dr2 (final 1x1: bf16 out WITHOUT relu -> B2)
    k_mconv<0, false, false, false, true, true><<<512, 128, 0, stream>>>(B0, wpk_dr23, nullptr, nullptr, nullptr, B1);
    k_mconv<1, false, true, false, true, false><<<512, 128, 0, stream>>>(B1, wpk_dr21, nullptr, F0, nullptr, B2);
    // deconv1: B2 -> N64 (bf16 NHWC 64x64)
    k_mconv<3, true, false, false, true, false><<<2048, 128, 0, stream>>>(B2, wpk_dc1, dt1_b, nullptr, nullptr, N64);
    // deconv2 + tanh -> recon
    k_deconv2n<<<2048, 256, 0, stream>>>(N64, w2pk, dt2_b, recon);
}

// Round 3
// 1302.581 us; speedup vs baseline: 7.7873x; 1.3092x over previous
//
#include <hip/hip_runtime.h>
#include <math.h>

// VQ-VAE forward. Heavy convs (Cin=Cout=256) via bf16 MFMA implicit GEMM.
// deconv2 (256->3) as wave-per-pixel coalesced VALU reduction.

typedef unsigned short ushort;
typedef short bf16x8 __attribute__((ext_vector_type(8)));
typedef float f32x4 __attribute__((ext_vector_type(4)));

__device__ __forceinline__ ushort f2bf(float f) {
    unsigned u = __builtin_bit_cast(unsigned, f);
    unsigned r = (u + 0x7fffu + ((u >> 16) & 1u)) >> 16;
    return (ushort)r;
}
__device__ __forceinline__ float bfl(unsigned u) { return __builtin_bit_cast(float, u << 16); }
__device__ __forceinline__ float bfh(unsigned u) { return __builtin_bit_cast(float, u & 0xffff0000u); }

// ======================= weight packing =======================
// MFMA layout (per layer): [cls][tap][cb(8)][co(256)][k(32)] bf16.

__global__ void k_pack_c3x4(const float* __restrict__ w0, const float* __restrict__ w1,
                            const float* __restrict__ w2, const float* __restrict__ w3,
                            ushort* __restrict__ o0, ushort* __restrict__ o1,
                            ushort* __restrict__ o2, ushort* __restrict__ o3) {
    int layer = blockIdx.x / 2304;
    int i = (blockIdx.x - layer * 2304) * 256 + threadIdx.x;     // 9*8*256*32 = 589824
    const float* w = layer == 0 ? w0 : layer == 1 ? w1 : layer == 2 ? w2 : w3;
    ushort* o = layer == 0 ? o0 : layer == 1 ? o1 : layer == 2 ? o2 : o3;
    int kk = i & 31, co = (i >> 5) & 255, cb = (i >> 13) & 7, t = i >> 16;
    int ci = cb * 32 + kk, kh = t / 3, kw = t % 3;
    o[i] = f2bf(w[((co * 256 + ci) * 3 + kh) * 3 + kw]);
}

__global__ void k_pack_c1x1x4(const float* __restrict__ w0, const float* __restrict__ w1,
                              const float* __restrict__ w2, const float* __restrict__ w3,
                              ushort* __restrict__ o0, ushort* __restrict__ o1,
                              ushort* __restrict__ o2, ushort* __restrict__ o3) {
    int layer = blockIdx.x >> 8;
    int i = (blockIdx.x & 255) * 256 + threadIdx.x;              // 8*256*32 = 65536
    const float* w = layer == 0 ? w0 : layer == 1 ? w1 : layer == 2 ? w2 : w3;
    ushort* o = layer == 0 ? o0 : layer == 1 ? o1 : layer == 2 ? o2 : o3;
    int kk = i & 31, co = (i >> 5) & 255, cb = (i >> 13) & 7;
    o[i] = f2bf(w[co * 256 + cb * 32 + kk]);
}

__global__ void k_pack_c2dc1(const float* __restrict__ wc2, const float* __restrict__ wdc1,
                             ushort* __restrict__ oc2, ushort* __restrict__ odc1) {
    int g = blockIdx.x;
    int layer = g >> 12;
    int i = (g & 4095) * 256 + threadIdx.x;                      // 4*4*8*256*32 = 1048576
    int kk = i & 31, co = (i >> 5) & 255, cb = (i >> 13) & 7;
    int t = (i >> 16) & 3, cls = i >> 18;
    int a = t >> 1, b = t & 1, ci = cb * 32 + kk;
    if (layer == 0) {
        int ph = cls >> 1, pw = cls & 1;
        int kh = ph ? 2 * a : 2 * a + 1;
        int kw = pw ? 2 * b : 2 * b + 1;
        oc2[i] = f2bf(wc2[((co * 256 + ci) * 4 + kh) * 4 + kw]);
    } else {
        int py = cls >> 1, px = cls & 1;
        int kh0 = (py + 1) & 1, kw0 = (px + 1) & 1;
        odc1[i] = f2bf(wdc1[((ci * 256 + co) * 4 + kh0 + 2 * a) * 4 + kw0 + 2 * b]);
    }
}

__global__ void k_pack_c1f(const float* __restrict__ w, float* __restrict__ o) {
    int i = blockIdx.x * 256 + threadIdx.x;           // 48*256 = 12288
    int co = i & 255, k = i >> 8;
    int ci = k >> 4, kh = (k >> 2) & 3, kw = k & 3;
    o[k * 256 + co] = w[((co * 3 + ci) * 4 + kh) * 4 + kw];
}

// deconv2 weights: [cls][lane(64)][j(4)][t(4)][co(3)] f32, ci = 4*lane+j, t=2a+b
__global__ void k_pack_dc2(const float* __restrict__ w, float* __restrict__ o) {
    int i = blockIdx.x * 256 + threadIdx.x;           // 4*64*48 = 12288
    int co = i % 3;
    int t = (i / 3) & 3;
    int j = (i / 12) & 3;
    int lane = (i / 48) & 63;
    int cls = i / 3072;
    int ci = lane * 4 + j;
    int py = cls >> 1, px = cls & 1, a = t >> 1, b2 = t & 1;
    int kh0 = (py + 1) & 1, kw0 = (px + 1) & 1;
    o[i] = w[((ci * 3 + co) * 4 + kh0 + 2 * a) * 4 + kw0 + 2 * b2];
}

// ======================= conv1: 3->256 k4 s2, 128->64, direct fp32 =======================
__global__ __launch_bounds__(256) void k_conv1n(const float* __restrict__ x,
                                                const float* __restrict__ wt,   // [48][256] f32
                                                const float* __restrict__ bias,
                                                ushort* __restrict__ o) {       // NHWC64 bf16
    int b = blockIdx.x;                  // 32n * 64h
    int h = b & 63, n = b >> 6;
    int co = threadIdx.x;
    float wr[48];
#pragma unroll
    for (int k = 0; k < 48; ++k) wr[k] = wt[k * 256 + co];
    const float* xp = x + (long)n * 3 * 128 * 128;
    float bco = bias[co];
    for (int w = 0; w < 64; ++w) {
        float acc = bco;
#pragma unroll
        for (int ci = 0; ci < 3; ++ci)
#pragma unroll
            for (int kh = 0; kh < 4; ++kh) {
                int hi = 2 * h - 1 + kh;
                if ((unsigned)hi < 128u) {
                    const float* row = xp + (ci * 128 + hi) * 128;
#pragma unroll
                    for (int kw = 0; kw < 4; ++kw) {
                        int wi = 2 * w - 1 + kw;
                        if ((unsigned)wi < 128u) acc += row[wi] * wr[(ci * 4 + kh) * 4 + kw];
                    }
                }
            }
        o[(((long)n * 64 + h) * 64 + w) * 256 + co] = f2bf(acc);
    }
}

// ======================= unified MFMA conv =======================
// MODE 0: 3x3 pad1 (9 taps), in 32x32 NHWC
// MODE 1: 1x1
// MODE 2: conv2 4x4 s2 (4 phases x 4 taps), in 64x64 NHWC
// MODE 3: deconv1 per-parity (4 taps), in 32x32 NHWC, out 64x64 NHWC
// Block: 256 threads = 4 waves. Block tile 128co x 128m. Wave tile 64co x 64m.
#define SX_W   56
#define SX_ROW (34 * SX_W)

template <int MODE, bool HAS_BIAS, bool ADD_RES, bool WRITE_F32, bool WRITE_BF16, bool RELU_BF16>
__global__ __launch_bounds__(256, 2) void k_mconv(const ushort* __restrict__ xin,
                                                  const ushort* __restrict__ wpk,
                                                  const float* __restrict__ bias,
                                                  const float* __restrict__ res,
                                                  float* __restrict__ of32,
                                                  ushort* __restrict__ obf) {
    constexpr int NT = (MODE == 0) ? 9 : ((MODE == 1) ? 1 : 4);
    constexpr int NOUT = (MODE == 2) ? 32 : 8;

    __shared__ __align__(16) ushort sX[6 * SX_ROW];   // 6 rows x 34 wpad x (32ci+24pad)

    int tid = threadIdx.x;
    int lane = tid & 63, wv = tid >> 6;               // 4 waves
    int wvc = wv & 1, wvm = wv >> 1;
    int q = lane >> 4, l15 = lane & 15;
    int b = blockIdx.x;
    int mblk = b & 7, slab = (b >> 3) & 1;
    int cls = (MODE == 3) ? ((b >> 4) & 3) : 0;
    int n = (MODE == 3) ? (b >> 6) : (b >> 4);
    int h0 = mblk * 4;

    // zero the w-pad columns (c=0 and c=33), all 6 rows, ci 0..31
    for (int i = tid; i < 384; i += 256) {
        int r = i >> 6, rem = i & 63, cc = rem >> 5, ci = rem & 31;
        sX[(r * 34 + (cc ? 33 : 0)) * SX_W + ci] = 0;
    }

    // staging thread map: 2 row-halves x 32 w-positions x 4 ci-octets
    int ciq = (tid & 3) * 8;
    int wst = (tid >> 2) & 31;
    int rhalf = tid >> 7;

    // B-fragment LDS bases (tap offset added later)
    int bbase[4];
#pragma unroll
    for (int bt = 0; bt < 4; ++bt) {
        int mloc = wvm * 64 + bt * 16 + l15;          // 0..127 within block tile
        int ro = mloc >> 5, col = mloc & 31;
        bbase[bt] = ((ro + 1) * 34 + col + 1) * SX_W + q * 8;
    }

    f32x4 acc[4][4];
#pragma unroll
    for (int at = 0; at < 4; ++at)
#pragma unroll
        for (int bt = 0; bt < 4; ++bt) acc[at][bt] = 0.f;

    for (int it = 0; it < NOUT; ++it) {
        int cb = (MODE == 2) ? (it >> 2) : it;
        int ph = (MODE == 2) ? (it & 3) : 0;
        int ph_h = ph >> 1, ph_w = ph & 1;

        // ---- stage X tile (rows h0-1 .. h0+4), zero-filled outside image ----
#pragma unroll
        for (int rr = 0; rr < 3; ++rr) {
            int r = rr * 2 + rhalf;
            if (MODE == 1 && (r == 0 || r == 5)) continue;   // 1x1 uses rows 1..4 only
            int hh = h0 + r - 1;
            bool valid = (unsigned)hh < 32u;
            long off;
            if (MODE == 2)
                off = (((long)n * 64 + 2 * hh + ph_h) * 64 + (2 * wst + ph_w)) * 256 + cb * 32 + ciq;
            else
                off = (((long)n * 32 + hh) * 32 + wst) * 256 + cb * 32 + ciq;
            uint4 v;
            if (valid) v = *(const uint4*)(xin + off);
            else { v.x = 0; v.y = 0; v.z = 0; v.w = 0; }
            *(uint4*)&sX[(r * 34 + wst + 1) * SX_W + ciq] = v;
        }
        __syncthreads();

        for (int t = 0; t < NT; ++t) {
            int dy, dx;
            if (MODE == 0) { dy = t / 3 - 1; dx = t % 3 - 1; }
            else if (MODE == 1) { dy = 0; dx = 0; }
            else if (MODE == 2) { dy = (t >> 1) - ph_h; dx = (t & 1) - ph_w; }
            else { dy = (cls >> 1) - (t >> 1); dx = (cls & 1) - (t & 1); }

            int clsi = (MODE == 2) ? ph : cls;
            const ushort* wp = wpk +
                ((((long)(clsi * NT + t)) * 8 + cb) * 256 + slab * 128 + wvc * 64 + l15) * 32 + q * 8;
            bf16x8 af[4];
#pragma unroll
            for (int at = 0; at < 4; ++at) af[at] = *(const bf16x8*)(wp + at * 512);

            int doff = (dy * 34 + dx) * SX_W;
            bf16x8 bfr[4];
#pragma unroll
            for (int bt = 0; bt < 4; ++bt) bfr[bt] = *(const bf16x8*)&sX[bbase[bt] + doff];

#pragma unroll
            for (int at = 0; at < 4; ++at)
#pragma unroll
                for (int bt = 0; bt < 4; ++bt)
                    acc[at][bt] = __builtin_amdgcn_mfma_f32_16x16x32_bf16(af[at], bfr[bt],
                                                                          acc[at][bt], 0, 0, 0);
        }
        __syncthreads();
    }

    // ---- epilogue ----
    int co_base = slab * 128 + wvc * 64;
#pragma unroll
    for (int at = 0; at < 4; ++at) {
        int co_t = co_base + at * 16 + q * 4;
        float bv[4] = {0.f, 0.f, 0.f, 0.f};
        if (HAS_BIAS) {
            float4 b4 = *(const float4*)(bias + co_t);
            bv[0] = b4.x; bv[1] = b4.y; bv[2] = b4.z; bv[3] = b4.w;
        }
#pragma unroll
        for (int bt = 0; bt < 4; ++bt) {
            int m = mblk * 128 + wvm * 64 + bt * 16 + l15;   // position within 32x32 image
            float v[4];
#pragma unroll
            for (int r = 0; r < 4; ++r) v[r] = acc[at][bt][r] + bv[r];
            if (ADD_RES) {
#pragma unroll
                for (int r = 0; r < 4; ++r)
                    v[r] += res[((long)(n * 256 + co_t + r)) * 1024 + m];
            }
            if (WRITE_F32) {
#pragma unroll
                for (int r = 0; r < 4; ++r)
                    of32[((long)(n * 256 + co_t + r)) * 1024 + m] = v[r];
            }
            if (WRITE_BF16) {
                unsigned p0, p1;
                {
                    float z0 = RELU_BF16 ? fmaxf(v[0], 0.f) : v[0];
                    float z1 = RELU_BF16 ? fmaxf(v[1], 0.f) : v[1];
                    float z2 = RELU_BF16 ? fmaxf(v[2], 0.f) : v[2];
                    float z3 = RELU_BF16 ? fmaxf(v[3], 0.f) : v[3];
                    p0 = (unsigned)f2bf(z0) | ((unsigned)f2bf(z1) << 16);
                    p1 = (unsigned)f2bf(z2) | ((unsigned)f2bf(z3) << 16);
                }
                long oaddr;
                if (MODE == 3) {
                    int oy = m >> 5, ox = m & 31;
                    int py = cls >> 1, px = cls & 1;
                    oaddr = (((long)n * 64 + 2 * oy + py) * 64 + 2 * ox + px) * 256 + co_t;
                } else {
                    oaddr = ((long)n * 1024 + m) * 256 + co_t;
                }
                uint2 pk; pk.x = p0; pk.y = p1;
                *(uint2*)(obf + oaddr) = pk;
            }
        }
    }
}

// ======================= VQ =======================
__global__ __launch_bounds__(256) void k_vq(const float* __restrict__ z,
                                            const float* __restrict__ cbk,
                                            float* __restrict__ vqf,     // fp32 NCHW
                                            ushort* __restrict__ vqb,    // bf16 NHWC, relu
                                            float* __restrict__ loss) {
    int t = blockIdx.x * 256 + threadIdx.x;
    int w = t & 31, h = (t >> 5) & 31, n = (t >> 10) & 31, g = t >> 15;
    const float* zp = z + ((n * 256 + g * 64) * 32 + h) * 32 + w;
    float zv[64];
#pragma unroll
    for (int j = 0; j < 64; ++j) zv[j] = zp[j * 1024];
    float best = 3.4e38f;
    int bi = 0;
    for (int k = 0; k < 256; ++k) {
        const float* e = cbk + k * 64;
        float d = 0.f;
#pragma unroll
        for (int j = 0; j < 64; ++j) {
            float df = zv[j] - e[j];
            d += df * df;
        }
        if (d < best) { best = d; bi = k; }
    }
    const float* e = cbk + bi * 64;
    float* vp = vqf + ((n * 256 + g * 64) * 32 + h) * 32 + w;
    ushort* bp = vqb + (((long)n * 32 + h) * 32 + w) * 256 + g * 64;
#pragma unroll
    for (int j = 0; j < 64; ++j) vp[j * 1024] = e[j];
#pragma unroll
    for (int j = 0; j < 64; j += 4) {
        uint2 pk;
        pk.x = (unsigned)f2bf(fmaxf(e[j], 0.f)) | ((unsigned)f2bf(fmaxf(e[j + 1], 0.f)) << 16);
        pk.y = (unsigned)f2bf(fmaxf(e[j + 2], 0.f)) | ((unsigned)f2bf(fmaxf(e[j + 3], 0.f)) << 16);
        *(uint2*)(bp + j) = pk;
    }
    float l = best;
#pragma unroll
    for (int off = 32; off > 0; off >>= 1) l += __shfl_down(l, off);
    __shared__ float ls[4];
    if ((threadIdx.x & 63) == 0) ls[threadIdx.x >> 6] = l;
    __syncthreads();
    if (threadIdx.x == 0)
        atomicAdd(loss, (ls[0] + ls[1] + ls[2] + ls[3]) * (1.25f / 8388608.f));
}

// ======================= deconv2: 256->3, 64->128, tanh (wave-per-pixel) =======================
__global__ __launch_bounds__(256) void k_deconv2w(const ushort* __restrict__ xin,  // NHWC64 bf16
                                                  const float* __restrict__ w2,    // [cls][64][4][4][3] f32
                                                  const float* __restrict__ bias,
                                                  float* __restrict__ o) {
    // grid: 32n * 4cls * 64oy = 8192 ; block 256 = 4 waves ; wave: 16 ox (2 per iter)
    int b = blockIdx.x;
    int oy = b & 63, cls = (b >> 6) & 3, n = b >> 8;
    int px = cls & 1, py = cls >> 1;
    int tid = threadIdx.x, lane = tid & 63, wv = tid >> 6;

    // 48 weight floats per lane (ci = 4*lane .. 4*lane+3)
    float wr[48];
    {
        const float* wl = w2 + ((long)cls * 64 + lane) * 48;
#pragma unroll
        for (int i = 0; i < 48; i += 4) {
            float4 f = *(const float4*)(wl + i);
            wr[i] = f.x; wr[i + 1] = f.y; wr[i + 2] = f.z; wr[i + 3] = f.w;
        }
    }
    int hiA = py ? oy + 1 : oy, hiB = hiA - 1;
    bool vA = (unsigned)hiA < 64u, vB = (unsigned)hiB < 64u;
    const ushort* base = xin + (long)n * 64 * 64 * 256 + lane * 4;
    const ushort* rA = base + (long)hiA * 64 * 256;
    const ushort* rB = base + (long)hiB * 64 * 256;
    float b0 = bias[0], b1 = bias[1], b2 = bias[2];
    int ho = 2 * oy + py;
    float* orow = o + ((long)n * 3 * 128 + ho) * 128 + px;

    for (int it = 0; it < 8; ++it) {
        int ox0 = wv * 16 + it * 2;
        float s[6] = {0.f, 0.f, 0.f, 0.f, 0.f, 0.f};
#pragma unroll
        for (int p = 0; p < 2; ++p) {
            int ox = ox0 + p;
            int wiA = px ? ox + 1 : ox, wiB = wiA - 1;
            bool uA = (unsigned)wiA < 64u, uB = (unsigned)wiB < 64u;
            uint2 z2; z2.x = 0; z2.y = 0;
            uint2 xt[4];
            xt[0] = (vA && uA) ? *(const uint2*)(rA + wiA * 256) : z2;
            xt[1] = (vA && uB) ? *(const uint2*)(rA + wiB * 256) : z2;
            xt[2] = (vB && uA) ? *(const uint2*)(rB + wiA * 256) : z2;
            xt[3] = (vB && uB) ? *(const uint2*)(rB + wiB * 256) : z2;
            float s0 = 0.f, s1 = 0.f, s2 = 0.f;
#pragma unroll
            for (int t = 0; t < 4; ++t) {
                unsigned u0 = xt[t].x, u1 = xt[t].y;
#pragma unroll
                for (int j = 0; j < 4; ++j) {
                    unsigned uu = (j >> 1) ? u1 : u0;
                    float x = (j & 1) ? bfh(uu) : bfl(uu);
                    const float* wp = wr + (j * 4 + t) * 3;
                    s0 += x * wp[0]; s1 += x * wp[1]; s2 += x * wp[2];
                }
            }
            s[p * 3 + 0] = s0; s[p * 3 + 1] = s1; s[p * 3 + 2] = s2;
        }
        // butterfly-reduce all 6 accumulators across the wave
#pragma unroll
        for (int m = 1; m < 64; m <<= 1) {
#pragma unroll
            for (int k = 0; k < 6; ++k) s[k] += __shfl_xor(s[k], m);
        }
        if (lane == 0) {
            orow[2 * ox0] = tanhf(s[0] + b0);
            orow[16384 + 2 * ox0] = tanhf(s[1] + b1);
            orow[32768 + 2 * ox0] = tanhf(s[2] + b2);
            orow[2 * ox0 + 2] = tanhf(s[3] + b0);
            orow[16384 + 2 * ox0 + 2] = tanhf(s[4] + b1);
            orow[32768 + 2 * ox0 + 2] = tanhf(s[5] + b2);
        }
    }
}

// ======================= launcher =======================
extern "C" void kernel_launch(void* const* d_in, const int* in_sizes, int n_in,
                              void* d_out, int out_size, void* d_ws, size_t ws_size,
                              hipStream_t stream) {
    (void)in_sizes; (void)n_in; (void)out_size; (void)ws_size;
    const float* x        = (const float*)d_in[0];
    const float* enc_w1   = (const float*)d_in[1];
    const float* enc_b1   = (const float*)d_in[2];
    const float* enc_w2   = (const float*)d_in[3];
    const float* enc_b2   = (const float*)d_in[4];
    const float* er1_w3   = (const float*)d_in[5];
    const float* er1_w1   = (const float*)d_in[6];
    const float* er2_w3   = (const float*)d_in[7];
    const float* er2_w1   = (const float*)d_in[8];
    const float* codebook = (const float*)d_in[9];
    const float* dr1_w3   = (const float*)d_in[10];
    const float* dr1_w1   = (const float*)d_in[11];
    const float* dr2_w3   = (const float*)d_in[12];
    const float* dr2_w1   = (const float*)d_in[13];
    const float* dt1_w    = (const float*)d_in[14];
    const float* dt1_b    = (const float*)d_in[15];
    const float* dt2_w    = (const float*)d_in[16];
    const float* dt2_b    = (const float*)d_in[17];

    float* recon = (float*)d_out;
    float* loss  = recon + 1572864;

    char* ws = (char*)d_ws;
    size_t off = 0;
    auto alloc = [&](size_t bytes) { char* p = ws + off; off += (bytes + 255) & ~(size_t)255; return p; };
    ushort* N64  = (ushort*)alloc(67108864);   // [32,64,64,256] bf16 (conv1 out, later deconv1 out)
    float*  F0   = (float*)alloc(33554432);    // fp32 NCHW rotating
    float*  F1   = (float*)alloc(33554432);
    ushort* B0   = (ushort*)alloc(16777216);   // bf16 NHWC 32x32 rotating
    ushort* B1   = (ushort*)alloc(16777216);
    ushort* B2   = (ushort*)alloc(16777216);
    ushort* wpk_c2   = (ushort*)alloc(2097152);
    ushort* wpk_dc1  = (ushort*)alloc(2097152);
    ushort* wpk_er13 = (ushort*)alloc(1179648);
    ushort* wpk_er23 = (ushort*)alloc(1179648);
    ushort* wpk_dr13 = (ushort*)alloc(1179648);
    ushort* wpk_dr23 = (ushort*)alloc(1179648);
    ushort* wpk_er11 = (ushort*)alloc(131072);
    ushort* wpk_er21 = (ushort*)alloc(131072);
    ushort* wpk_dr11 = (ushort*)alloc(131072);
    ushort* wpk_dr21 = (ushort*)alloc(131072);
    float*  wt_c1    = (float*)alloc(49152);
    float*  w2pk     = (float*)alloc(49152);

    hipMemsetAsync(loss, 0, sizeof(float), stream);

    // weight packing (fused)
    k_pack_c1f<<<48, 256, 0, stream>>>(enc_w1, wt_c1);
    k_pack_c2dc1<<<8192, 256, 0, stream>>>(enc_w2, dt1_w, wpk_c2, wpk_dc1);
    k_pack_c3x4<<<9216, 256, 0, stream>>>(er1_w3, er2_w3, dr1_w3, dr2_w3,
                                          wpk_er13, wpk_er23, wpk_dr13, wpk_dr23);
    k_pack_c1x1x4<<<1024, 256, 0, stream>>>(er1_w1, er2_w1, dr1_w1, dr2_w1,
                                            wpk_er11, wpk_er21, wpk_dr11, wpk_dr21);
    k_pack_dc2<<<48, 256, 0, stream>>>(dt2_w, w2pk);

    // encoder
    k_conv1n<<<2048, 256, 0, stream>>>(x, wt_c1, enc_b1, N64);
    // conv2: N64 -> F0 (fp32) + B0 (bf16 relu)
    k_mconv<2, true, false, true, true, true><<<512, 256, 0, stream>>>(N64, wpk_c2, enc_b2, nullptr, F0, B0);
    // er1
    k_mconv<0, false, false, false, true, true><<<512, 256, 0, stream>>>(B0, wpk_er13, nullptr, nullptr, nullptr, B1);
    k_mconv<1, false, true, true, true, true><<<512, 256, 0, stream>>>(B1, wpk_er11, nullptr, F0, F1, B0);
    // er2
    k_mconv<0, false, false, false, true, true><<<512, 256, 0, stream>>>(B0, wpk_er23, nullptr, nullptr, nullptr, B1);
    k_mconv<1, false, true, true, false, false><<<512, 256, 0, stream>>>(B1, wpk_er21, nullptr, F1, F0, nullptr);
    // VQ: F0 -> F1 (fp32) + B0 (bf16 relu) + loss
    k_vq<<<512, 256, 0, stream>>>(F0, codebook, F1, B0, loss);
    // dr1
    k_mconv<0, false, false, false, true, true><<<512, 256, 0, stream>>>(B0, wpk_dr13, nullptr, nullptr, nullptr, B1);
    k_mconv<1, false, true, true, true, true><<<512, 256, 0, stream>>>(B1, wpk_dr11, nullptr, F1, F0, B0);
    // dr2 (final 1x1: bf16 out WITHOUT relu -> B2)
    k_mconv<0, false, false, false, true, true><<<512, 256, 0, stream>>>(B0, wpk_dr23, nullptr, nullptr, nullptr, B1);
    k_mconv<1, false, true, false, true, false><<<512, 256, 0, stream>>>(B1, wpk_dr21, nullptr, F0, nullptr, B2);
    // deconv1: B2 -> N64 (bf16 NHWC 64x64)
    k_mconv<3, true, false, false, true, false><<<2048, 256, 0, stream>>>(B2, wpk_dc1, dt1_b, nullptr, nullptr, N64);
    // deconv2 + tanh -> recon
    k_deconv2w<<<8192, 256, 0, stream>>>(N64, w2pk, dt2_b, recon);
}

// Round 4
// 1060.332 us; speedup vs baseline: 9.5664x; 1.2285x over previous
//
#include <hip/hip_runtime.h>
#include <math.h>

// VQ-VAE forward. Heavy convs (Cin=Cout=256) via bf16 MFMA implicit GEMM.
// R4: bank-conflict-free mconv LDS layout, MFMA-based VQ, LDS-staged conv1.

typedef unsigned short ushort;
typedef short bf16x8 __attribute__((ext_vector_type(8)));
typedef float f32x4 __attribute__((ext_vector_type(4)));

__device__ __forceinline__ ushort f2bf(float f) {
    unsigned u = __builtin_bit_cast(unsigned, f);
    unsigned r = (u + 0x7fffu + ((u >> 16) & 1u)) >> 16;
    return (ushort)r;
}
__device__ __forceinline__ float bfl(unsigned u) { return __builtin_bit_cast(float, u << 16); }
__device__ __forceinline__ float bfh(unsigned u) { return __builtin_bit_cast(float, u & 0xffff0000u); }

// ======================= weight packing =======================
// MFMA layout (per layer): [cls][tap][cb(8)][co(256)][k(32)] bf16.

__global__ void k_pack_c3x4(const float* __restrict__ w0, const float* __restrict__ w1,
                            const float* __restrict__ w2, const float* __restrict__ w3,
                            ushort* __restrict__ o0, ushort* __restrict__ o1,
                            ushort* __restrict__ o2, ushort* __restrict__ o3) {
    int layer = blockIdx.x / 2304;
    int i = (blockIdx.x - layer * 2304) * 256 + threadIdx.x;     // 9*8*256*32 = 589824
    const float* w = layer == 0 ? w0 : layer == 1 ? w1 : layer == 2 ? w2 : w3;
    ushort* o = layer == 0 ? o0 : layer == 1 ? o1 : layer == 2 ? o2 : o3;
    int kk = i & 31, co = (i >> 5) & 255, cb = (i >> 13) & 7, t = i >> 16;
    int ci = cb * 32 + kk, kh = t / 3, kw = t % 3;
    o[i] = f2bf(w[((co * 256 + ci) * 3 + kh) * 3 + kw]);
}

__global__ void k_pack_c1x1x4(const float* __restrict__ w0, const float* __restrict__ w1,
                              const float* __restrict__ w2, const float* __restrict__ w3,
                              ushort* __restrict__ o0, ushort* __restrict__ o1,
                              ushort* __restrict__ o2, ushort* __restrict__ o3) {
    int layer = blockIdx.x >> 8;
    int i = (blockIdx.x & 255) * 256 + threadIdx.x;              // 8*256*32 = 65536
    const float* w = layer == 0 ? w0 : layer == 1 ? w1 : layer == 2 ? w2 : w3;
    ushort* o = layer == 0 ? o0 : layer == 1 ? o1 : layer == 2 ? o2 : o3;
    int kk = i & 31, co = (i >> 5) & 255, cb = (i >> 13) & 7;
    o[i] = f2bf(w[co * 256 + cb * 32 + kk]);
}

__global__ void k_pack_c2dc1(const float* __restrict__ wc2, const float* __restrict__ wdc1,
                             ushort* __restrict__ oc2, ushort* __restrict__ odc1) {
    int g = blockIdx.x;
    int layer = g >> 12;
    int i = (g & 4095) * 256 + threadIdx.x;                      // 4*4*8*256*32 = 1048576
    int kk = i & 31, co = (i >> 5) & 255, cb = (i >> 13) & 7;
    int t = (i >> 16) & 3, cls = i >> 18;
    int a = t >> 1, b = t & 1, ci = cb * 32 + kk;
    if (layer == 0) {
        int ph = cls >> 1, pw = cls & 1;
        int kh = ph ? 2 * a : 2 * a + 1;
        int kw = pw ? 2 * b : 2 * b + 1;
        oc2[i] = f2bf(wc2[((co * 256 + ci) * 4 + kh) * 4 + kw]);
    } else {
        int py = cls >> 1, px = cls & 1;
        int kh0 = (py + 1) & 1, kw0 = (px + 1) & 1;
        odc1[i] = f2bf(wdc1[((ci * 256 + co) * 4 + kh0 + 2 * a) * 4 + kw0 + 2 * b]);
    }
}

__global__ void k_pack_c1f(const float* __restrict__ w, float* __restrict__ o) {
    int i = blockIdx.x * 256 + threadIdx.x;           // 48*256 = 12288
    int co = i & 255, k = i >> 8;
    int ci = k >> 4, kh = (k >> 2) & 3, kw = k & 3;
    o[k * 256 + co] = w[((co * 3 + ci) * 4 + kh) * 4 + kw];
}

// deconv2 weights: [cls][lane(64)][j(4)][t(4)][co(3)] f32, ci = 4*lane+j, t=2a+b
__global__ void k_pack_dc2(const float* __restrict__ w, float* __restrict__ o) {
    int i = blockIdx.x * 256 + threadIdx.x;           // 4*64*48 = 12288
    int co = i % 3;
    int t = (i / 3) & 3;
    int j = (i / 12) & 3;
    int lane = (i / 48) & 63;
    int cls = i / 3072;
    int ci = lane * 4 + j;
    int py = cls >> 1, px = cls & 1, a = t >> 1, b2 = t & 1;
    int kh0 = (py + 1) & 1, kw0 = (px + 1) & 1;
    o[i] = w[((ci * 3 + co) * 4 + kh0 + 2 * a) * 4 + kw0 + 2 * b2];
}

// VQ codebook prepack: apk [tile(16)][kstep(2)][lane(64)][8] bf16 ; en [256] fp32
__global__ void k_pack_vq(const float* __restrict__ cb, ushort* __restrict__ apk,
                          float* __restrict__ en) {
    if (blockIdx.x < 64) {
        int i = blockIdx.x * 256 + threadIdx.x;       // 0..16383
        int j = i & 7, lane = (i >> 3) & 63, s = (i >> 9) & 1, t = i >> 10;
        int code = t * 16 + (lane & 15);
        int dim = s * 32 + (lane >> 4) * 8 + j;
        apk[i] = f2bf(cb[code * 64 + dim]);
    } else {
        int code = threadIdx.x;
        float s = 0.f;
        for (int d = 0; d < 64; ++d) { float v = cb[code * 64 + d]; s += v * v; }
        en[code] = s;
    }
}

// ======================= conv1: 3->256 k4 s2, 128->64, LDS-staged =======================
__global__ __launch_bounds__(256) void k_conv1n(const float* __restrict__ x,
                                                const float* __restrict__ wt,   // [48][256] f32
                                                const float* __restrict__ bias,
                                                ushort* __restrict__ o) {       // NHWC64 bf16
    __shared__ float sx[12][132];        // [ci*4+kh][wi+1], zero pads at 0 and 129
    int b = blockIdx.x;                  // 32n * 64h
    int h = b & 63, n = b >> 6;
    int tid = threadIdx.x;
    for (int c = tid; c < 12 * 128; c += 256) {
        int t = c >> 7, wi = c & 127;
        int ci = t >> 2, kh = t & 3;
        int hi = 2 * h - 1 + kh;
        float v = ((unsigned)hi < 128u) ? x[((long)n * 3 + ci) * 16384 + hi * 128 + wi] : 0.f;
        sx[t][wi + 1] = v;
    }
    if (tid < 24) { int t = tid >> 1; sx[t][(tid & 1) ? 129 : 0] = 0.f; }
    int co = tid;
    float wr[48];
#pragma unroll
    for (int k = 0; k < 48; ++k) wr[k] = wt[k * 256 + co];
    float bco = bias[co];
    __syncthreads();
    ushort* op = o + (((long)n * 64 + h) * 64) * 256 + co;
    for (int w = 0; w < 64; ++w) {
        float acc = bco;
#pragma unroll
        for (int t = 0; t < 12; ++t) {
            const float* xr = &sx[t][2 * w];
            acc += xr[0] * wr[t * 4] + xr[1] * wr[t * 4 + 1]
                 + xr[2] * wr[t * 4 + 2] + xr[3] * wr[t * 4 + 3];
        }
        op[w * 256] = f2bf(acc);
    }
}

// ======================= unified MFMA conv =======================
// MODE 0: 3x3 pad1 (9 taps), in 32x32 NHWC
// MODE 1: 1x1
// MODE 2: conv2 4x4 s2 (4 phases x 4 taps), in 64x64 NHWC
// MODE 3: deconv1 per-parity (4 taps), in 32x32 NHWC, out 64x64 NHWC
// Block: 256 threads = 4 waves. Block tile 128co x 128m. Wave tile 64co x 64m.
// LDS layout: [row r(6)][k-octet q(4)][col c(34)][8 ushorts] -> bank-conflict-free
// (16-lane phases cover 64 consecutive dwords = 2-deep per bank = free).
#define SXE(r, q, c) (((((r) << 2) + (q)) * 34 + (c)) << 3)

template <int MODE, bool HAS_BIAS, bool ADD_RES, bool WRITE_F32, bool WRITE_BF16, bool RELU_BF16>
__global__ __launch_bounds__(256, 2) void k_mconv(const ushort* __restrict__ xin,
                                                  const ushort* __restrict__ wpk,
                                                  const float* __restrict__ bias,
                                                  const float* __restrict__ res,
                                                  float* __restrict__ of32,
                                                  ushort* __restrict__ obf) {
    constexpr int NT = (MODE == 0) ? 9 : ((MODE == 1) ? 1 : 4);
    constexpr int NOUT = (MODE == 2) ? 32 : 8;

    __shared__ __align__(16) ushort sX[6 * 4 * 34 * 8];   // 13056 B

    int tid = threadIdx.x;
    int lane = tid & 63, wv = tid >> 6;               // 4 waves
    int wvc = wv & 1, wvm = wv >> 1;
    int q = lane >> 4, l15 = lane & 15;
    int b = blockIdx.x;
    int mblk = b & 7, slab = (b >> 3) & 1;
    int cls = (MODE == 3) ? ((b >> 4) & 3) : 0;
    int n = (MODE == 3) ? (b >> 6) : (b >> 4);
    int h0 = mblk * 4;

    // zero the c-pad columns (c=0 and c=33), all r,q
    if (tid < 48) {
        int r = tid / 8, rem = tid & 7, qq = rem >> 1, cc = (rem & 1) ? 33 : 0;
        uint4 z; z.x = z.y = z.z = z.w = 0;
        *(uint4*)&sX[SXE(r, qq, cc)] = z;
    }

    // staging thread map: 2 row-halves x 32 w-positions x 4 ci-octets
    int qsel = tid & 3;
    int ciq = qsel * 8;
    int wst = (tid >> 2) & 31;
    int rhalf = tid >> 7;

    // B-fragment LDS bases (tap offset added later)
    int bbase[4];
#pragma unroll
    for (int bt = 0; bt < 4; ++bt) {
        int mloc = wvm * 64 + bt * 16 + l15;          // 0..127 within block tile
        int ro = mloc >> 5, col = mloc & 31;
        bbase[bt] = SXE(ro + 1, q, col + 1);
    }

    f32x4 acc[4][4];
#pragma unroll
    for (int at = 0; at < 4; ++at)
#pragma unroll
        for (int bt = 0; bt < 4; ++bt) acc[at][bt] = 0.f;

    for (int it = 0; it < NOUT; ++it) {
        int cb = (MODE == 2) ? (it >> 2) : it;
        int ph = (MODE == 2) ? (it & 3) : 0;
        int ph_h = ph >> 1, ph_w = ph & 1;

        // ---- stage X tile (rows h0-1 .. h0+4), zero-filled outside image ----
#pragma unroll
        for (int rr = 0; rr < 3; ++rr) {
            int r = rr * 2 + rhalf;
            if (MODE == 1 && (r == 0 || r == 5)) continue;   // 1x1 uses rows 1..4 only
            int hh = h0 + r - 1;
            bool valid = (unsigned)hh < 32u;
            long off;
            if (MODE == 2)
                off = (((long)n * 64 + 2 * hh + ph_h) * 64 + (2 * wst + ph_w)) * 256 + cb * 32 + ciq;
            else
                off = (((long)n * 32 + hh) * 32 + wst) * 256 + cb * 32 + ciq;
            uint4 v;
            if (valid) v = *(const uint4*)(xin + off);
            else { v.x = 0; v.y = 0; v.z = 0; v.w = 0; }
            *(uint4*)&sX[SXE(r, qsel, wst + 1)] = v;
        }
        __syncthreads();

        for (int t = 0; t < NT; ++t) {
            int dy, dx;
            if (MODE == 0) { dy = t / 3 - 1; dx = t % 3 - 1; }
            else if (MODE == 1) { dy = 0; dx = 0; }
            else if (MODE == 2) { dy = (t >> 1) - ph_h; dx = (t & 1) - ph_w; }
            else { dy = (cls >> 1) - (t >> 1); dx = (cls & 1) - (t & 1); }

            int clsi = (MODE == 2) ? ph : cls;
            const ushort* wp = wpk +
                ((((long)(clsi * NT + t)) * 8 + cb) * 256 + slab * 128 + wvc * 64 + l15) * 32 + q * 8;
            bf16x8 af[4];
#pragma unroll
            for (int at = 0; at < 4; ++at) af[at] = *(const bf16x8*)(wp + at * 512);

            int doff = (dy * 4 * 34 + dx) * 8;
            bf16x8 bfr[4];
#pragma unroll
            for (int bt = 0; bt < 4; ++bt) bfr[bt] = *(const bf16x8*)&sX[bbase[bt] + doff];

#pragma unroll
            for (int at = 0; at < 4; ++at)
#pragma unroll
                for (int bt = 0; bt < 4; ++bt)
                    acc[at][bt] = __builtin_amdgcn_mfma_f32_16x16x32_bf16(af[at], bfr[bt],
                                                                          acc[at][bt], 0, 0, 0);
        }
        __syncthreads();
    }

    // ---- epilogue ----
    int co_base = slab * 128 + wvc * 64;
#pragma unroll
    for (int at = 0; at < 4; ++at) {
        int co_t = co_base + at * 16 + q * 4;
        float bv[4] = {0.f, 0.f, 0.f, 0.f};
        if (HAS_BIAS) {
            float4 b4 = *(const float4*)(bias + co_t);
            bv[0] = b4.x; bv[1] = b4.y; bv[2] = b4.z; bv[3] = b4.w;
        }
#pragma unroll
        for (int bt = 0; bt < 4; ++bt) {
            int m = mblk * 128 + wvm * 64 + bt * 16 + l15;   // position within 32x32 image
            float v[4];
#pragma unroll
            for (int r = 0; r < 4; ++r) v[r] = acc[at][bt][r] + bv[r];
            if (ADD_RES) {
#pragma unroll
                for (int r = 0; r < 4; ++r)
                    v[r] += res[((long)(n * 256 + co_t + r)) * 1024 + m];
            }
            if (WRITE_F32) {
#pragma unroll
                for (int r = 0; r < 4; ++r)
                    of32[((long)(n * 256 + co_t + r)) * 1024 + m] = v[r];
            }
            if (WRITE_BF16) {
                unsigned p0, p1;
                {
                    float z0 = RELU_BF16 ? fmaxf(v[0], 0.f) : v[0];
                    float z1 = RELU_BF16 ? fmaxf(v[1], 0.f) : v[1];
                    float z2 = RELU_BF16 ? fmaxf(v[2], 0.f) : v[2];
                    float z3 = RELU_BF16 ? fmaxf(v[3], 0.f) : v[3];
                    p0 = (unsigned)f2bf(z0) | ((unsigned)f2bf(z1) << 16);
                    p1 = (unsigned)f2bf(z2) | ((unsigned)f2bf(z3) << 16);
                }
                long oaddr;
                if (MODE == 3) {
                    int oy = m >> 5, ox = m & 31;
                    int py = cls >> 1, px = cls & 1;
                    oaddr = (((long)n * 64 + 2 * oy + py) * 64 + 2 * ox + px) * 256 + co_t;
                } else {
                    oaddr = ((long)n * 1024 + m) * 256 + co_t;
                }
                uint2 pk; pk.x = p0; pk.y = p1;
                *(uint2*)(obf + oaddr) = pk;
            }
        }
    }
}

// ======================= VQ via MFMA =======================
// zb: [131072 rows][64] bf16 (row = pixel*4 + g, NHWC order)
// S = z . e^T via 16x16x32 bf16 MFMA; argmin(||e||^2 - 2S); loss = best + ||z||^2.
__global__ __launch_bounds__(256) void k_vq2(const ushort* __restrict__ zb,
                                             const ushort* __restrict__ apk,  // [16][2][64][8]
                                             const float* __restrict__ en,    // [256]
                                             const float* __restrict__ cbf,   // [256][64] fp32
                                             float* __restrict__ vqf,         // fp32 NCHW
                                             ushort* __restrict__ vqb,        // bf16 NHWC relu
                                             float* __restrict__ loss) {
    __shared__ int sIdx[64];
    __shared__ float sLoss[64];
    int tid = threadIdx.x, lane = tid & 63, wv = tid >> 6;
    int q = lane >> 4, l15 = lane & 15;
    int r0 = blockIdx.x * 64;
    int R = r0 + wv * 16;

    const ushort* zp = zb + ((long)(R + l15)) * 64 + q * 8;
    bf16x8 b0 = *(const bf16x8*)zp;
    bf16x8 b1 = *(const bf16x8*)(zp + 32);

    float z2 = 0.f;
    {
        const unsigned* u0 = (const unsigned*)&b0;
        const unsigned* u1 = (const unsigned*)&b1;
#pragma unroll
        for (int i = 0; i < 4; ++i) {
            float a = bfl(u0[i]), bb = bfh(u0[i]);
            float c = bfl(u1[i]), d = bfh(u1[i]);
            z2 += a * a + bb * bb + c * c + d * d;
        }
    }

    float best = 3.4e38f;
    int bidx = 0;
#pragma unroll
    for (int t = 0; t < 16; ++t) {
        bf16x8 a0 = *(const bf16x8*)(apk + ((t * 2 + 0) * 64 + lane) * 8);
        bf16x8 a1 = *(const bf16x8*)(apk + ((t * 2 + 1) * 64 + lane) * 8);
        f32x4 acc = {0.f, 0.f, 0.f, 0.f};
        acc = __builtin_amdgcn_mfma_f32_16x16x32_bf16(a0, b0, acc, 0, 0, 0);
        acc = __builtin_amdgcn_mfma_f32_16x16x32_bf16(a1, b1, acc, 0, 0, 0);
        float4 e4 = *(const float4*)(en + t * 16 + q * 4);
        float sc[4] = {e4.x - 2.f * acc[0], e4.y - 2.f * acc[1],
                       e4.z - 2.f * acc[2], e4.w - 2.f * acc[3]};
#pragma unroll
        for (int r = 0; r < 4; ++r) {
            int code = t * 16 + q * 4 + r;
            if (sc[r] < best) { best = sc[r]; bidx = code; }   // ascending scan -> first-min
        }
    }
    // reduce across the 4 q-lanes sharing this row (xor 16, 32), tie -> lowest idx
#pragma unroll
    for (int m = 16; m <= 32; m <<= 1) {
        float ob = __shfl_xor(best, m);
        int oi = __shfl_xor(bidx, m);
        if (ob < best || (ob == best && oi < bidx)) { best = ob; bidx = oi; }
        z2 += __shfl_xor(z2, m);
    }
    if (q == 0) {
        sIdx[wv * 16 + l15] = bidx;
        sLoss[wv * 16 + l15] = best + z2;
    }
    __syncthreads();

    // loss reduction (wave 0)
    if (wv == 0) {
        float l = sLoss[lane];
#pragma unroll
        for (int m = 1; m < 64; m <<= 1) l += __shfl_xor(l, m);
        if (lane == 0) atomicAdd(loss, l * (1.25f / 8388608.f));
    }

    // vq_st fp32 NCHW writes (coalesced 64B segments)
    int p0 = blockIdx.x * 16;            // block pixel base (16 pixels x 4 g)
    int n = p0 >> 10, hw = p0 & 1023;
    long base = ((long)n * 256) * 1024 + hw;
#pragma unroll
    for (int k = 0; k < 16; ++k) {
        int i = k * 256 + tid;           // 0..4095
        int pl = i & 15, gj = i >> 4;    // gj = g*64 + j
        int g = gj >> 6, j = gj & 63;
        int idx = sIdx[pl * 4 + g];
        vqf[base + (long)gj * 1024 + pl] = cbf[idx * 64 + j];
    }
    // relu(vq) bf16 NHWC writes (coalesced)
    unsigned* vb = (unsigned*)(vqb + (long)r0 * 64);
#pragma unroll
    for (int k = 0; k < 8; ++k) {
        int i = k * 256 + tid;           // 0..2047 uints
        int rl = i >> 5, jp = i & 31;
        int idx = sIdx[rl];
        float v0 = fmaxf(cbf[idx * 64 + 2 * jp], 0.f);
        float v1 = fmaxf(cbf[idx * 64 + 2 * jp + 1], 0.f);
        vb[i] = (unsigned)f2bf(v0) | ((unsigned)f2bf(v1) << 16);
    }
}

// ======================= deconv2: 256->3, 64->128, tanh (wave-per-pixel) =======================
__global__ __launch_bounds__(256) void k_deconv2w(const ushort* __restrict__ xin,  // NHWC64 bf16
                                                  const float* __restrict__ w2,    // [cls][64][4][4][3] f32
                                                  const float* __restrict__ bias,
                                                  float* __restrict__ o) {
    int b = blockIdx.x;
    int oy = b & 63, cls = (b >> 6) & 3, n = b >> 8;
    int px = cls & 1, py = cls >> 1;
    int tid = threadIdx.x, lane = tid & 63, wv = tid >> 6;

    float wr[48];
    {
        const float* wl = w2 + ((long)cls * 64 + lane) * 48;
#pragma unroll
        for (int i = 0; i < 48; i += 4) {
            float4 f = *(const float4*)(wl + i);
            wr[i] = f.x; wr[i + 1] = f.y; wr[i + 2] = f.z; wr[i + 3] = f.w;
        }
    }
    int hiA = py ? oy + 1 : oy, hiB = hiA - 1;
    bool vA = (unsigned)hiA < 64u, vB = (unsigned)hiB < 64u;
    const ushort* base = xin + (long)n * 64 * 64 * 256 + lane * 4;
    const ushort* rA = base + (long)hiA * 64 * 256;
    const ushort* rB = base + (long)hiB * 64 * 256;
    float b0 = bias[0], b1 = bias[1], b2 = bias[2];
    int ho = 2 * oy + py;
    float* orow = o + ((long)n * 3 * 128 + ho) * 128 + px;

    for (int it = 0; it < 8; ++it) {
        int ox0 = wv * 16 + it * 2;
        float s[6] = {0.f, 0.f, 0.f, 0.f, 0.f, 0.f};
#pragma unroll
        for (int p = 0; p < 2; ++p) {
            int ox = ox0 + p;
            int wiA = px ? ox + 1 : ox, wiB = wiA - 1;
            bool uA = (unsigned)wiA < 64u, uB = (unsigned)wiB < 64u;
            uint2 z2; z2.x = 0; z2.y = 0;
            uint2 xt[4];
            xt[0] = (vA && uA) ? *(const uint2*)(rA + wiA * 256) : z2;
            xt[1] = (vA && uB) ? *(const uint2*)(rA + wiB * 256) : z2;
            xt[2] = (vB && uA) ? *(const uint2*)(rB + wiA * 256) : z2;
            xt[3] = (vB && uB) ? *(const uint2*)(rB + wiB * 256) : z2;
            float s0 = 0.f, s1 = 0.f, s2 = 0.f;
#pragma unroll
            for (int t = 0; t < 4; ++t) {
                unsigned u0 = xt[t].x, u1 = xt[t].y;
#pragma unroll
                for (int j = 0; j < 4; ++j) {
                    unsigned uu = (j >> 1) ? u1 : u0;
                    float x = (j & 1) ? bfh(uu) : bfl(uu);
                    const float* wp = wr + (j * 4 + t) * 3;
                    s0 += x * wp[0]; s1 += x * wp[1]; s2 += x * wp[2];
                }
            }
            s[p * 3 + 0] = s0; s[p * 3 + 1] = s1; s[p * 3 + 2] = s2;
        }
#pragma unroll
        for (int m = 1; m < 64; m <<= 1) {
#pragma unroll
            for (int k = 0; k < 6; ++k) s[k] += __shfl_xor(s[k], m);
        }
        if (lane == 0) {
            orow[2 * ox0] = tanhf(s[0] + b0);
            orow[16384 + 2 * ox0] = tanhf(s[1] + b1);
            orow[32768 + 2 * ox0] = tanhf(s[2] + b2);
            orow[2 * ox0 + 2] = tanhf(s[3] + b0);
            orow[16384 + 2 * ox0 + 2] = tanhf(s[4] + b1);
            orow[32768 + 2 * ox0 + 2] = tanhf(s[5] + b2);
        }
    }
}

// ======================= launcher =======================
extern "C" void kernel_launch(void* const* d_in, const int* in_sizes, int n_in,
                              void* d_out, int out_size, void* d_ws, size_t ws_size,
                              hipStream_t stream) {
    (void)in_sizes; (void)n_in; (void)out_size; (void)ws_size;
    const float* x        = (const float*)d_in[0];
    const float* enc_w1   = (const float*)d_in[1];
    const float* enc_b1   = (const float*)d_in[2];
    const float* enc_w2   = (const float*)d_in[3];
    const float* enc_b2   = (const float*)d_in[4];
    const float* er1_w3   = (const float*)d_in[5];
    const float* er1_w1   = (const float*)d_in[6];
    const float* er2_w3   = (const float*)d_in[7];
    const float* er2_w1   = (const float*)d_in[8];
    const float* codebook = (const float*)d_in[9];
    const float* dr1_w3   = (const float*)d_in[10];
    const float* dr1_w1   = (const float*)d_in[11];
    const float* dr2_w3   = (const float*)d_in[12];
    const float* dr2_w1   = (const float*)d_in[13];
    const float* dt1_w    = (const float*)d_in[14];
    const float* dt1_b    = (const float*)d_in[15];
    const float* dt2_w    = (const float*)d_in[16];
    const float* dt2_b    = (const float*)d_in[17];

    float* recon = (float*)d_out;
    float* loss  = recon + 1572864;

    char* ws = (char*)d_ws;
    size_t off = 0;
    auto alloc = [&](size_t bytes) { char* p = ws + off; off += (bytes + 255) & ~(size_t)255; return p; };
    ushort* N64  = (ushort*)alloc(67108864);   // [32,64,64,256] bf16 (conv1 out, later deconv1 out)
    float*  F0   = (float*)alloc(33554432);    // fp32 NCHW rotating
    float*  F1   = (float*)alloc(33554432);
    ushort* B0   = (ushort*)alloc(16777216);   // bf16 NHWC 32x32 rotating
    ushort* B1   = (ushort*)alloc(16777216);
    ushort* B2   = (ushort*)alloc(16777216);
    ushort* wpk_c2   = (ushort*)alloc(2097152);
    ushort* wpk_dc1  = (ushort*)alloc(2097152);
    ushort* wpk_er13 = (ushort*)alloc(1179648);
    ushort* wpk_er23 = (ushort*)alloc(1179648);
    ushort* wpk_dr13 = (ushort*)alloc(1179648);
    ushort* wpk_dr23 = (ushort*)alloc(1179648);
    ushort* wpk_er11 = (ushort*)alloc(131072);
    ushort* wpk_er21 = (ushort*)alloc(131072);
    ushort* wpk_dr11 = (ushort*)alloc(131072);
    ushort* wpk_dr21 = (ushort*)alloc(131072);
    float*  wt_c1    = (float*)alloc(49152);
    float*  w2pk     = (float*)alloc(49152);
    ushort* apk      = (ushort*)alloc(32768);
    float*  en       = (float*)alloc(1024);

    hipMemsetAsync(loss, 0, sizeof(float), stream);

    // weight packing
    k_pack_c1f<<<48, 256, 0, stream>>>(enc_w1, wt_c1);
    k_pack_c2dc1<<<8192, 256, 0, stream>>>(enc_w2, dt1_w, wpk_c2, wpk_dc1);
    k_pack_c3x4<<<9216, 256, 0, stream>>>(er1_w3, er2_w3, dr1_w3, dr2_w3,
                                          wpk_er13, wpk_er23, wpk_dr13, wpk_dr23);
    k_pack_c1x1x4<<<1024, 256, 0, stream>>>(er1_w1, er2_w1, dr1_w1, dr2_w1,
                                            wpk_er11, wpk_er21, wpk_dr11, wpk_dr21);
    k_pack_dc2<<<48, 256, 0, stream>>>(dt2_w, w2pk);
    k_pack_vq<<<65, 256, 0, stream>>>(codebook, apk, en);

    // encoder
    k_conv1n<<<2048, 256, 0, stream>>>(x, wt_c1, enc_b1, N64);
    // conv2: N64 -> F0 (fp32) + B0 (bf16 relu)
    k_mconv<2, true, false, true, true, true><<<512, 256, 0, stream>>>(N64, wpk_c2, enc_b2, nullptr, F0, B0);
    // er1
    k_mconv<0, false, false, false, true, true><<<512, 256, 0, stream>>>(B0, wpk_er13, nullptr, nullptr, nullptr, B1);
    k_mconv<1, false, true, true, true, true><<<512, 256, 0, stream>>>(B1, wpk_er11, nullptr, F0, F1, B0);
    // er2 (1x1 emits bf16 z NHWC for VQ, no relu)
    k_mconv<0, false, false, false, true, true><<<512, 256, 0, stream>>>(B0, wpk_er23, nullptr, nullptr, nullptr, B1);
    k_mconv<1, false, true, false, true, false><<<512, 256, 0, stream>>>(B1, wpk_er21, nullptr, F1, nullptr, B2);
    // VQ: B2 (z bf16) -> F1 (vq fp32 NCHW) + B0 (relu vq bf16 NHWC) + loss
    k_vq2<<<2048, 256, 0, stream>>>(B2, apk, en, codebook, F1, B0, loss);
    // dr1
    k_mconv<0, false, false, false, true, true><<<512, 256, 0, stream>>>(B0, wpk_dr13, nullptr, nullptr, nullptr, B1);
    k_mconv<1, false, true, true, true, true><<<512, 256, 0, stream>>>(B1, wpk_dr11, nullptr, F1, F0, B0);
    // dr2 (final 1x1: bf16 out WITHOUT relu -> B2)
    k_mconv<0, false, false, false, true, true><<<512, 256, 0, stream>>>(B0, wpk_dr23, nullptr, nullptr, nullptr, B1);
    k_mconv<1, false, true, false, true, false><<<512, 256, 0, stream>>>(B1, wpk_dr21, nullptr, F0, nullptr, B2);
    // deconv1: B2 -> N64 (bf16 NHWC 64x64)
    k_mconv<3, true, false, false, true, false><<<2048, 256, 0, stream>>>(B2, wpk_dc1, dt1_b, nullptr, nullptr, N64);
    // deconv2 + tanh -> recon
    k_deconv2w<<<8192, 256, 0, stream>>>(N64, w2pk, dt2_b, recon);
}

// Round 7
// 938.892 us; speedup vs baseline: 10.8038x; 1.1293x over previous
//
#include <hip/hip_runtime.h>
#include <math.h>

// VQ-VAE forward. All Cin=256 convs (incl. deconv2's 256->3 via zero-padded
// co-tile of 16) on bf16 MFMA implicit GEMM.
// (Resubmission: R5/R6 benches failed on MI355X container acquisition —
// infra error, kernel never executed. Source unchanged to isolate.)

typedef unsigned short ushort;
typedef short bf16x8 __attribute__((ext_vector_type(8)));
typedef float f32x4 __attribute__((ext_vector_type(4)));

__device__ __forceinline__ ushort f2bf(float f) {
    unsigned u = __builtin_bit_cast(unsigned, f);
    unsigned r = (u + 0x7fffu + ((u >> 16) & 1u)) >> 16;
    return (ushort)r;
}
__device__ __forceinline__ float bfl(unsigned u) { return __builtin_bit_cast(float, u << 16); }
__device__ __forceinline__ float bfh(unsigned u) { return __builtin_bit_cast(float, u & 0xffff0000u); }

// ======================= weight packing =======================
// MFMA layout (per layer): [cls][tap][cb(8)][co(256)][k(32)] bf16.

__global__ void k_pack_c3x4(const float* __restrict__ w0, const float* __restrict__ w1,
                            const float* __restrict__ w2, const float* __restrict__ w3,
                            ushort* __restrict__ o0, ushort* __restrict__ o1,
                            ushort* __restrict__ o2, ushort* __restrict__ o3) {
    int layer = blockIdx.x / 2304;
    int i = (blockIdx.x - layer * 2304) * 256 + threadIdx.x;     // 9*8*256*32 = 589824
    const float* w = layer == 0 ? w0 : layer == 1 ? w1 : layer == 2 ? w2 : w3;
    ushort* o = layer == 0 ? o0 : layer == 1 ? o1 : layer == 2 ? o2 : o3;
    int kk = i & 31, co = (i >> 5) & 255, cb = (i >> 13) & 7, t = i >> 16;
    int ci = cb * 32 + kk, kh = t / 3, kw = t % 3;
    o[i] = f2bf(w[((co * 256 + ci) * 3 + kh) * 3 + kw]);
}

__global__ void k_pack_c1x1x4(const float* __restrict__ w0, const float* __restrict__ w1,
                              const float* __restrict__ w2, const float* __restrict__ w3,
                              ushort* __restrict__ o0, ushort* __restrict__ o1,
                              ushort* __restrict__ o2, ushort* __restrict__ o3) {
    int layer = blockIdx.x >> 8;
    int i = (blockIdx.x & 255) * 256 + threadIdx.x;              // 8*256*32 = 65536
    const float* w = layer == 0 ? w0 : layer == 1 ? w1 : layer == 2 ? w2 : w3;
    ushort* o = layer == 0 ? o0 : layer == 1 ? o1 : layer == 2 ? o2 : o3;
    int kk = i & 31, co = (i >> 5) & 255, cb = (i >> 13) & 7;
    o[i] = f2bf(w[co * 256 + cb * 32 + kk]);
}

__global__ void k_pack_c2dc1(const float* __restrict__ wc2, const float* __restrict__ wdc1,
                             ushort* __restrict__ oc2, ushort* __restrict__ odc1) {
    int g = blockIdx.x;
    int layer = g >> 12;
    int i = (g & 4095) * 256 + threadIdx.x;                      // 4*4*8*256*32 = 1048576
    int kk = i & 31, co = (i >> 5) & 255, cb = (i >> 13) & 7;
    int t = (i >> 16) & 3, cls = i >> 18;
    int a = t >> 1, b = t & 1, ci = cb * 32 + kk;
    if (layer == 0) {
        int ph = cls >> 1, pw = cls & 1;
        int kh = ph ? 2 * a : 2 * a + 1;
        int kw = pw ? 2 * b : 2 * b + 1;
        oc2[i] = f2bf(wc2[((co * 256 + ci) * 4 + kh) * 4 + kw]);
    } else {
        int py = cls >> 1, px = cls & 1;
        int kh0 = (py + 1) & 1, kw0 = (px + 1) & 1;
        odc1[i] = f2bf(wdc1[((ci * 256 + co) * 4 + kh0 + 2 * a) * 4 + kw0 + 2 * b]);
    }
}

__global__ void k_pack_c1f(const float* __restrict__ w, float* __restrict__ o) {
    int i = blockIdx.x * 256 + threadIdx.x;           // 48*256 = 12288
    int co = i & 255, k = i >> 8;
    int ci = k >> 4, kh = (k >> 2) & 3, kw = k & 3;
    o[k * 256 + co] = w[((co * 3 + ci) * 4 + kh) * 4 + kw];
}

// deconv2 MFMA weights: [tap(9)][cb(8)][oc(16)][k(32)] bf16, oc = cls*3+co (12
// used, 4 zero). Tap (dy,dx) reads input (u+dy, v+dx); kernel elem kh=1+py-2dy,
// kw=1+px-2dx, zero when outside [0,4).
__global__ void k_pack_dc2m(const float* __restrict__ w, ushort* __restrict__ o) {
    int i = blockIdx.x * 256 + threadIdx.x;           // 9*8*16*32 = 36864
    int kk = i & 31, oc = (i >> 5) & 15, cb = (i >> 9) & 7, t = i >> 12;
    int dy = t / 3 - 1, dx = t % 3 - 1;
    int ci = cb * 32 + kk;
    float v = 0.f;
    if (oc < 12) {
        int cls = oc / 3, co = oc - cls * 3;
        int py = cls >> 1, px = cls & 1;
        int kh = 1 + py - 2 * dy, kw = 1 + px - 2 * dx;
        if ((unsigned)kh < 4u && (unsigned)kw < 4u)
            v = w[((ci * 3 + co) * 4 + kh) * 4 + kw];
    }
    o[i] = f2bf(v);
}

// VQ codebook prepack: apk [tile(16)][kstep(2)][lane(64)][8] bf16 ; en [256] fp32
__global__ void k_pack_vq(const float* __restrict__ cb, ushort* __restrict__ apk,
                          float* __restrict__ en) {
    if (blockIdx.x < 64) {
        int i = blockIdx.x * 256 + threadIdx.x;       // 0..16383
        int j = i & 7, lane = (i >> 3) & 63, s = (i >> 9) & 1, t = i >> 10;
        int code = t * 16 + (lane & 15);
        int dim = s * 32 + (lane >> 4) * 8 + j;
        apk[i] = f2bf(cb[code * 64 + dim]);
    } else {
        int code = threadIdx.x;
        float s = 0.f;
        for (int d = 0; d < 64; ++d) { float v = cb[code * 64 + d]; s += v * v; }
        en[code] = s;
    }
}

// ======================= conv1: 3->256 k4 s2, 128->64, LDS-staged =======================
__global__ __launch_bounds__(256) void k_conv1n(const float* __restrict__ x,
                                                const float* __restrict__ wt,   // [48][256] f32
                                                const float* __restrict__ bias,
                                                ushort* __restrict__ o) {       // NHWC64 bf16
    __shared__ float sx[12][132];
    int b = blockIdx.x;                  // 32n * 64h
    int h = b & 63, n = b >> 6;
    int tid = threadIdx.x;
    for (int c = tid; c < 12 * 128; c += 256) {
        int t = c >> 7, wi = c & 127;
        int ci = t >> 2, kh = t & 3;
        int hi = 2 * h - 1 + kh;
        float v = ((unsigned)hi < 128u) ? x[((long)n * 3 + ci) * 16384 + hi * 128 + wi] : 0.f;
        sx[t][wi + 1] = v;
    }
    if (tid < 24) { int t = tid >> 1; sx[t][(tid & 1) ? 129 : 0] = 0.f; }
    int co = tid;
    float wr[48];
#pragma unroll
    for (int k = 0; k < 48; ++k) wr[k] = wt[k * 256 + co];
    float bco = bias[co];
    __syncthreads();
    ushort* op = o + (((long)n * 64 + h) * 64) * 256 + co;
    for (int w = 0; w < 64; ++w) {
        float acc = bco;
#pragma unroll
        for (int t = 0; t < 12; ++t) {
            const float* xr = &sx[t][2 * w];
            acc += xr[0] * wr[t * 4] + xr[1] * wr[t * 4 + 1]
                 + xr[2] * wr[t * 4 + 2] + xr[3] * wr[t * 4 + 3];
        }
        op[w * 256] = f2bf(acc);
    }
}

// ======================= unified MFMA conv =======================
// MODE 0: 3x3 pad1 (9 taps), in 32x32 NHWC
// MODE 1: 1x1
// MODE 2: conv2 4x4 s2 (4 phases x 4 taps), in 64x64 NHWC
// MODE 3: deconv1 per-parity (4 taps), in 32x32 NHWC, out 64x64 NHWC
// Block: 256 threads = 4 waves. Block tile 128co x 128m. Wave tile 64co x 64m.
// LDS layout: [row r(6)][k-octet q(4)][col c(34)][8 ushorts] -> conflict-free.
#define SXE(r, q, c) (((((r) << 2) + (q)) * 34 + (c)) << 3)

template <int MODE, bool HAS_BIAS, bool ADD_RES, bool WRITE_F32, bool WRITE_BF16, bool RELU_BF16>
__global__ __launch_bounds__(256, 2) void k_mconv(const ushort* __restrict__ xin,
                                                  const ushort* __restrict__ wpk,
                                                  const float* __restrict__ bias,
                                                  const float* __restrict__ res,
                                                  float* __restrict__ of32,
                                                  ushort* __restrict__ obf) {
    constexpr int NT = (MODE == 0) ? 9 : ((MODE == 1) ? 1 : 4);
    constexpr int NOUT = (MODE == 2) ? 32 : 8;

    __shared__ __align__(16) ushort sX[6 * 4 * 34 * 8];   // 13056 B

    int tid = threadIdx.x;
    int lane = tid & 63, wv = tid >> 6;               // 4 waves
    int wvc = wv & 1, wvm = wv >> 1;
    int q = lane >> 4, l15 = lane & 15;
    int b = blockIdx.x;
    int mblk = b & 7, slab = (b >> 3) & 1;
    int cls = (MODE == 3) ? ((b >> 4) & 3) : 0;
    int n = (MODE == 3) ? (b >> 6) : (b >> 4);
    int h0 = mblk * 4;

    if (tid < 48) {
        int r = tid / 8, rem = tid & 7, qq = rem >> 1, cc = (rem & 1) ? 33 : 0;
        uint4 z; z.x = z.y = z.z = z.w = 0;
        *(uint4*)&sX[SXE(r, qq, cc)] = z;
    }

    int qsel = tid & 3;
    int ciq = qsel * 8;
    int wst = (tid >> 2) & 31;
    int rhalf = tid >> 7;

    int bbase[4];
#pragma unroll
    for (int bt = 0; bt < 4; ++bt) {
        int mloc = wvm * 64 + bt * 16 + l15;
        int ro = mloc >> 5, col = mloc & 31;
        bbase[bt] = SXE(ro + 1, q, col + 1);
    }

    f32x4 acc[4][4];
#pragma unroll
    for (int at = 0; at < 4; ++at)
#pragma unroll
        for (int bt = 0; bt < 4; ++bt) acc[at][bt] = 0.f;

    for (int it = 0; it < NOUT; ++it) {
        int cb = (MODE == 2) ? (it >> 2) : it;
        int ph = (MODE == 2) ? (it & 3) : 0;
        int ph_h = ph >> 1, ph_w = ph & 1;

#pragma unroll
        for (int rr = 0; rr < 3; ++rr) {
            int r = rr * 2 + rhalf;
            if (MODE == 1 && (r == 0 || r == 5)) continue;
            int hh = h0 + r - 1;
            bool valid = (unsigned)hh < 32u;
            long off;
            if (MODE == 2)
                off = (((long)n * 64 + 2 * hh + ph_h) * 64 + (2 * wst + ph_w)) * 256 + cb * 32 + ciq;
            else
                off = (((long)n * 32 + hh) * 32 + wst) * 256 + cb * 32 + ciq;
            uint4 v;
            if (valid) v = *(const uint4*)(xin + off);
            else { v.x = 0; v.y = 0; v.z = 0; v.w = 0; }
            *(uint4*)&sX[SXE(r, qsel, wst + 1)] = v;
        }
        __syncthreads();

        for (int t = 0; t < NT; ++t) {
            int dy, dx;
            if (MODE == 0) { dy = t / 3 - 1; dx = t % 3 - 1; }
            else if (MODE == 1) { dy = 0; dx = 0; }
            else if (MODE == 2) { dy = (t >> 1) - ph_h; dx = (t & 1) - ph_w; }
            else { dy = (cls >> 1) - (t >> 1); dx = (cls & 1) - (t & 1); }

            int clsi = (MODE == 2) ? ph : cls;
            const ushort* wp = wpk +
                ((((long)(clsi * NT + t)) * 8 + cb) * 256 + slab * 128 + wvc * 64 + l15) * 32 + q * 8;
            bf16x8 af[4];
#pragma unroll
            for (int at = 0; at < 4; ++at) af[at] = *(const bf16x8*)(wp + at * 512);

            int doff = (dy * 4 * 34 + dx) * 8;
            bf16x8 bfr[4];
#pragma unroll
            for (int bt = 0; bt < 4; ++bt) bfr[bt] = *(const bf16x8*)&sX[bbase[bt] + doff];

#pragma unroll
            for (int at = 0; at < 4; ++at)
#pragma unroll
                for (int bt = 0; bt < 4; ++bt)
                    acc[at][bt] = __builtin_amdgcn_mfma_f32_16x16x32_bf16(af[at], bfr[bt],
                                                                          acc[at][bt], 0, 0, 0);
        }
        __syncthreads();
    }

    int co_base = slab * 128 + wvc * 64;
#pragma unroll
    for (int at = 0; at < 4; ++at) {
        int co_t = co_base + at * 16 + q * 4;
        float bv[4] = {0.f, 0.f, 0.f, 0.f};
        if (HAS_BIAS) {
            float4 b4 = *(const float4*)(bias + co_t);
            bv[0] = b4.x; bv[1] = b4.y; bv[2] = b4.z; bv[3] = b4.w;
        }
#pragma unroll
        for (int bt = 0; bt < 4; ++bt) {
            int m = mblk * 128 + wvm * 64 + bt * 16 + l15;
            float v[4];
#pragma unroll
            for (int r = 0; r < 4; ++r) v[r] = acc[at][bt][r] + bv[r];
            if (ADD_RES) {
#pragma unroll
                for (int r = 0; r < 4; ++r)
                    v[r] += res[((long)(n * 256 + co_t + r)) * 1024 + m];
            }
            if (WRITE_F32) {
#pragma unroll
                for (int r = 0; r < 4; ++r)
                    of32[((long)(n * 256 + co_t + r)) * 1024 + m] = v[r];
            }
            if (WRITE_BF16) {
                unsigned p0, p1;
                {
                    float z0 = RELU_BF16 ? fmaxf(v[0], 0.f) : v[0];
                    float z1 = RELU_BF16 ? fmaxf(v[1], 0.f) : v[1];
                    float z2 = RELU_BF16 ? fmaxf(v[2], 0.f) : v[2];
                    float z3 = RELU_BF16 ? fmaxf(v[3], 0.f) : v[3];
                    p0 = (unsigned)f2bf(z0) | ((unsigned)f2bf(z1) << 16);
                    p1 = (unsigned)f2bf(z2) | ((unsigned)f2bf(z3) << 16);
                }
                long oaddr;
                if (MODE == 3) {
                    int oy = m >> 5, ox = m & 31;
                    int py = cls >> 1, px = cls & 1;
                    oaddr = (((long)n * 64 + 2 * oy + py) * 64 + 2 * ox + px) * 256 + co_t;
                } else {
                    oaddr = ((long)n * 1024 + m) * 256 + co_t;
                }
                uint2 pk; pk.x = p0; pk.y = p1;
                *(uint2*)(obf + oaddr) = pk;
            }
        }
    }
}

// ======================= VQ via MFMA =======================
__global__ __launch_bounds__(256) void k_vq2(const ushort* __restrict__ zb,
                                             const ushort* __restrict__ apk,  // [16][2][64][8]
                                             const float* __restrict__ en,    // [256]
                                             const float* __restrict__ cbf,   // [256][64] fp32
                                             float* __restrict__ vqf,         // fp32 NCHW
                                             ushort* __restrict__ vqb,        // bf16 NHWC relu
                                             float* __restrict__ loss) {
    __shared__ int sIdx[64];
    __shared__ float sLoss[64];
    int tid = threadIdx.x, lane = tid & 63, wv = tid >> 6;
    int q = lane >> 4, l15 = lane & 15;
    int r0 = blockIdx.x * 64;
    int R = r0 + wv * 16;

    const ushort* zp = zb + ((long)(R + l15)) * 64 + q * 8;
    bf16x8 b0 = *(const bf16x8*)zp;
    bf16x8 b1 = *(const bf16x8*)(zp + 32);

    float z2 = 0.f;
    {
        const unsigned* u0 = (const unsigned*)&b0;
        const unsigned* u1 = (const unsigned*)&b1;
#pragma unroll
        for (int i = 0; i < 4; ++i) {
            float a = bfl(u0[i]), bb = bfh(u0[i]);
            float c = bfl(u1[i]), d = bfh(u1[i]);
            z2 += a * a + bb * bb + c * c + d * d;
        }
    }

    float best = 3.4e38f;
    int bidx = 0;
#pragma unroll
    for (int t = 0; t < 16; ++t) {
        bf16x8 a0 = *(const bf16x8*)(apk + ((t * 2 + 0) * 64 + lane) * 8);
        bf16x8 a1 = *(const bf16x8*)(apk + ((t * 2 + 1) * 64 + lane) * 8);
        f32x4 acc = {0.f, 0.f, 0.f, 0.f};
        acc = __builtin_amdgcn_mfma_f32_16x16x32_bf16(a0, b0, acc, 0, 0, 0);
        acc = __builtin_amdgcn_mfma_f32_16x16x32_bf16(a1, b1, acc, 0, 0, 0);
        float4 e4 = *(const float4*)(en + t * 16 + q * 4);
        float sc[4] = {e4.x - 2.f * acc[0], e4.y - 2.f * acc[1],
                       e4.z - 2.f * acc[2], e4.w - 2.f * acc[3]};
#pragma unroll
        for (int r = 0; r < 4; ++r) {
            int code = t * 16 + q * 4 + r;
            if (sc[r] < best) { best = sc[r]; bidx = code; }
        }
    }
#pragma unroll
    for (int m = 16; m <= 32; m <<= 1) {
        float ob = __shfl_xor(best, m);
        int oi = __shfl_xor(bidx, m);
        if (ob < best || (ob == best && oi < bidx)) { best = ob; bidx = oi; }
        z2 += __shfl_xor(z2, m);
    }
    if (q == 0) {
        sIdx[wv * 16 + l15] = bidx;
        sLoss[wv * 16 + l15] = best + z2;
    }
    __syncthreads();

    if (wv == 0) {
        float l = sLoss[lane];
#pragma unroll
        for (int m = 1; m < 64; m <<= 1) l += __shfl_xor(l, m);
        if (lane == 0) atomicAdd(loss, l * (1.25f / 8388608.f));
    }

    int p0 = blockIdx.x * 16;
    int n = p0 >> 10, hw = p0 & 1023;
    long base = ((long)n * 256) * 1024 + hw;
#pragma unroll
    for (int k = 0; k < 16; ++k) {
        int i = k * 256 + tid;
        int pl = i & 15, gj = i >> 4;
        int g = gj >> 6, j = gj & 63;
        int idx = sIdx[pl * 4 + g];
        vqf[base + (long)gj * 1024 + pl] = cbf[idx * 64 + j];
    }
    unsigned* vb = (unsigned*)(vqb + (long)r0 * 64);
#pragma unroll
    for (int k = 0; k < 8; ++k) {
        int i = k * 256 + tid;
        int rl = i >> 5, jp = i & 31;
        int idx = sIdx[rl];
        float v0 = fmaxf(cbf[idx * 64 + 2 * jp], 0.f);
        float v1 = fmaxf(cbf[idx * 64 + 2 * jp + 1], 0.f);
        vb[i] = (unsigned)f2bf(v0) | ((unsigned)f2bf(v1) << 16);
    }
}

// ======================= deconv2 via MFMA: 256->3, 64->128, tanh =======================
// Implicit GEMM: oc(16: cls*3+co, 12 used) x m(input-grid pixels), K = 9 taps x 256.
// Block: 256 thr = 4 waves; M-tile = 256 px (4 rows x 64 cols of 64x64 grid).
#define SDE(r, q, c) (((((r) << 2) + (q)) * 66 + (c)) << 3)

__global__ __launch_bounds__(256, 2) void k_deconv2m(const ushort* __restrict__ xin,
                                                     const ushort* __restrict__ wpk, // [9][8][16][32]
                                                     const float* __restrict__ bias,
                                                     float* __restrict__ o) {
    __shared__ __align__(16) ushort sX[6 * 4 * 66 * 8];   // 25344 B

    int tid = threadIdx.x, lane = tid & 63, wv = tid >> 6;
    int q = lane >> 4, l15 = lane & 15;
    int b = blockIdx.x;                   // 32n * 16mt = 512
    int mt = b & 15, n = b >> 4;
    int h0 = mt * 4;

    // zero col pads c=0, c=65 for all (r,q)
    if (tid < 48) {
        int r = tid / 8, rem = tid & 7, qq = rem >> 1, cc = (rem & 1) ? 65 : 0;
        uint4 z; z.x = z.y = z.z = z.w = 0;
        *(uint4*)&sX[SDE(r, qq, cc)] = z;
    }

    int qsel = tid & 3, wst = (tid >> 2) & 63;

    int bbase[4];
#pragma unroll
    for (int bt = 0; bt < 4; ++bt) {
        int mloc = wv * 64 + bt * 16 + l15;       // 0..255
        int ro = mloc >> 6, col = mloc & 63;
        bbase[bt] = SDE(ro + 1, q, col + 1);
    }

    f32x4 acc[4];
#pragma unroll
    for (int bt = 0; bt < 4; ++bt) acc[bt] = 0.f;

    for (int cb = 0; cb < 8; ++cb) {
        // stage rows h0-1 .. h0+4
#pragma unroll
        for (int r = 0; r < 6; ++r) {
            int hh = h0 + r - 1;
            uint4 v;
            if ((unsigned)hh < 64u)
                v = *(const uint4*)(xin + (((long)n * 64 + hh) * 64 + wst) * 256 + cb * 32 + qsel * 8);
            else { v.x = 0; v.y = 0; v.z = 0; v.w = 0; }
            *(uint4*)&sX[SDE(r, qsel, wst + 1)] = v;
        }
        __syncthreads();

#pragma unroll
        for (int t = 0; t < 9; ++t) {
            int dy = t / 3 - 1, dx = t % 3 - 1;
            bf16x8 af = *(const bf16x8*)(wpk + (((t * 8 + cb) * 16 + l15) * 32 + q * 8));
            int doff = (dy * 4 * 66 + dx) * 8;
#pragma unroll
            for (int bt = 0; bt < 4; ++bt) {
                bf16x8 bf = *(const bf16x8*)&sX[bbase[bt] + doff];
                acc[bt] = __builtin_amdgcn_mfma_f32_16x16x32_bf16(af, bf, acc[bt], 0, 0, 0);
            }
        }
        __syncthreads();
    }

    // epilogue: oc = q*4+r (cls=oc/3, co=oc%3), skip oc>=12; out (2u+py, 2v+px)
    if (q < 3) {
#pragma unroll
        for (int bt = 0; bt < 4; ++bt) {
            int mloc = wv * 64 + bt * 16 + l15;
            int u = h0 + (mloc >> 6), v = mloc & 63;
#pragma unroll
            for (int r = 0; r < 4; ++r) {
                int oc = q * 4 + r;
                int cls = oc / 3, cs = oc - cls * 3;
                int py = cls >> 1, px = cls & 1;
                o[(((long)n * 3 + cs) * 128 + 2 * u + py) * 128 + 2 * v + px] =
                    tanhf(acc[bt][r] + bias[cs]);
            }
        }
    }
}

// ======================= launcher =======================
extern "C" void kernel_launch(void* const* d_in, const int* in_sizes, int n_in,
                              void* d_out, int out_size, void* d_ws, size_t ws_size,
                              hipStream_t stream) {
    (void)in_sizes; (void)n_in; (void)out_size; (void)ws_size;
    const float* x        = (const float*)d_in[0];
    const float* enc_w1   = (const float*)d_in[1];
    const float* enc_b1   = (const float*)d_in[2];
    const float* enc_w2   = (const float*)d_in[3];
    const float* enc_b2   = (const float*)d_in[4];
    const float* er1_w3   = (const float*)d_in[5];
    const float* er1_w1   = (const float*)d_in[6];
    const float* er2_w3   = (const float*)d_in[7];
    const float* er2_w1   = (const float*)d_in[8];
    const float* codebook = (const float*)d_in[9];
    const float* dr1_w3   = (const float*)d_in[10];
    const float* dr1_w1   = (const float*)d_in[11];
    const float* dr2_w3   = (const float*)d_in[12];
    const float* dr2_w1   = (const float*)d_in[13];
    const float* dt1_w    = (const float*)d_in[14];
    const float* dt1_b    = (const float*)d_in[15];
    const float* dt2_w    = (const float*)d_in[16];
    const float* dt2_b    = (const float*)d_in[17];

    float* recon = (float*)d_out;
    float* loss  = recon + 1572864;

    char* ws = (char*)d_ws;
    size_t off = 0;
    auto alloc = [&](size_t bytes) { char* p = ws + off; off += (bytes + 255) & ~(size_t)255; return p; };
    ushort* N64  = (ushort*)alloc(67108864);   // [32,64,64,256] bf16
    float*  F0   = (float*)alloc(33554432);
    float*  F1   = (float*)alloc(33554432);
    ushort* B0   = (ushort*)alloc(16777216);
    ushort* B1   = (ushort*)alloc(16777216);
    ushort* B2   = (ushort*)alloc(16777216);
    ushort* wpk_c2   = (ushort*)alloc(2097152);
    ushort* wpk_dc1  = (ushort*)alloc(2097152);
    ushort* wpk_er13 = (ushort*)alloc(1179648);
    ushort* wpk_er23 = (ushort*)alloc(1179648);
    ushort* wpk_dr13 = (ushort*)alloc(1179648);
    ushort* wpk_dr23 = (ushort*)alloc(1179648);
    ushort* wpk_er11 = (ushort*)alloc(131072);
    ushort* wpk_er21 = (ushort*)alloc(131072);
    ushort* wpk_dr11 = (ushort*)alloc(131072);
    ushort* wpk_dr21 = (ushort*)alloc(131072);
    float*  wt_c1    = (float*)alloc(49152);
    ushort* w2pk     = (ushort*)alloc(73728);
    ushort* apk      = (ushort*)alloc(32768);
    float*  en       = (float*)alloc(1024);

    hipMemsetAsync(loss, 0, sizeof(float), stream);

    // weight packing
    k_pack_c1f<<<48, 256, 0, stream>>>(enc_w1, wt_c1);
    k_pack_c2dc1<<<8192, 256, 0, stream>>>(enc_w2, dt1_w, wpk_c2, wpk_dc1);
    k_pack_c3x4<<<9216, 256, 0, stream>>>(er1_w3, er2_w3, dr1_w3, dr2_w3,
                                          wpk_er13, wpk_er23, wpk_dr13, wpk_dr23);
    k_pack_c1x1x4<<<1024, 256, 0, stream>>>(er1_w1, er2_w1, dr1_w1, dr2_w1,
                                            wpk_er11, wpk_er21, wpk_dr11, wpk_dr21);
    k_pack_dc2m<<<144, 256, 0, stream>>>(dt2_w, w2pk);
    k_pack_vq<<<65, 256, 0, stream>>>(codebook, apk, en);

    // encoder
    k_conv1n<<<2048, 256, 0, stream>>>(x, wt_c1, enc_b1, N64);
    k_mconv<2, true, false, true, true, true><<<512, 256, 0, stream>>>(N64, wpk_c2, enc_b2, nullptr, F0, B0);
    // er1
    k_mconv<0, false, false, false, true, true><<<512, 256, 0, stream>>>(B0, wpk_er13, nullptr, nullptr, nullptr, B1);
    k_mconv<1, false, true, true, true, true><<<512, 256, 0, stream>>>(B1, wpk_er11, nullptr, F0, F1, B0);
    // er2 (1x1 emits bf16 z NHWC for VQ, no relu)
    k_mconv<0, false, false, false, true, true><<<512, 256, 0, stream>>>(B0, wpk_er23, nullptr, nullptr, nullptr, B1);
    k_mconv<1, false, true, false, true, false><<<512, 256, 0, stream>>>(B1, wpk_er21, nullptr, F1, nullptr, B2);
    // VQ
    k_vq2<<<2048, 256, 0, stream>>>(B2, apk, en, codebook, F1, B0, loss);
    // dr1
    k_mconv<0, false, false, false, true, true><<<512, 256, 0, stream>>>(B0, wpk_dr13, nullptr, nullptr, nullptr, B1);
    k_mconv<1, false, true, true, true, true><<<512, 256, 0, stream>>>(B1, wpk_dr11, nullptr, F1, F0, B0);
    // dr2
    k_mconv<0, false, false, false, true, true><<<512, 256, 0, stream>>>(B0, wpk_dr23, nullptr, nullptr, nullptr, B1);
    k_mconv<1, false, true, false, true, false><<<512, 256, 0, stream>>>(B1, wpk_dr21, nullptr, F0, nullptr, B2);
    // deconv1
    k_mconv<3, true, false, false, true, false><<<2048, 256, 0, stream>>>(B2, wpk_dc1, dt1_b, nullptr, nullptr, N64);
    // deconv2 + tanh
    k_deconv2m<<<512, 256, 0, stream>>>(N64, w2pk, dt2_b, recon);
}

// Round 8
// 844.450 us; speedup vs baseline: 12.0120x; 1.1118x over previous
//
#include <hip/hip_runtime.h>
#include <math.h>

// VQ-VAE forward. All Cin=256 convs on bf16 MFMA implicit GEMM.
// R8: 2-wave mconv blocks (grid x2 -> 4+ blocks/CU), register software
// pipelining (staging prefetch across barrier + A-frag preload).

typedef unsigned short ushort;
typedef short bf16x8 __attribute__((ext_vector_type(8)));
typedef float f32x4 __attribute__((ext_vector_type(4)));

__device__ __forceinline__ ushort f2bf(float f) {
    unsigned u = __builtin_bit_cast(unsigned, f);
    unsigned r = (u + 0x7fffu + ((u >> 16) & 1u)) >> 16;
    return (ushort)r;
}
__device__ __forceinline__ float bfl(unsigned u) { return __builtin_bit_cast(float, u << 16); }
__device__ __forceinline__ float bfh(unsigned u) { return __builtin_bit_cast(float, u & 0xffff0000u); }

// ======================= weight packing =======================
// MFMA layout (per layer): [cls][tap][cb(8)][co(256)][k(32)] bf16.

__global__ void k_pack_c3x4(const float* __restrict__ w0, const float* __restrict__ w1,
                            const float* __restrict__ w2, const float* __restrict__ w3,
                            ushort* __restrict__ o0, ushort* __restrict__ o1,
                            ushort* __restrict__ o2, ushort* __restrict__ o3) {
    int layer = blockIdx.x / 2304;
    int i = (blockIdx.x - layer * 2304) * 256 + threadIdx.x;     // 9*8*256*32 = 589824
    const float* w = layer == 0 ? w0 : layer == 1 ? w1 : layer == 2 ? w2 : w3;
    ushort* o = layer == 0 ? o0 : layer == 1 ? o1 : layer == 2 ? o2 : o3;
    int kk = i & 31, co = (i >> 5) & 255, cb = (i >> 13) & 7, t = i >> 16;
    int ci = cb * 32 + kk, kh = t / 3, kw = t % 3;
    o[i] = f2bf(w[((co * 256 + ci) * 3 + kh) * 3 + kw]);
}

__global__ void k_pack_c1x1x4(const float* __restrict__ w0, const float* __restrict__ w1,
                              const float* __restrict__ w2, const float* __restrict__ w3,
                              ushort* __restrict__ o0, ushort* __restrict__ o1,
                              ushort* __restrict__ o2, ushort* __restrict__ o3) {
    int layer = blockIdx.x >> 8;
    int i = (blockIdx.x & 255) * 256 + threadIdx.x;              // 8*256*32 = 65536
    const float* w = layer == 0 ? w0 : layer == 1 ? w1 : layer == 2 ? w2 : w3;
    ushort* o = layer == 0 ? o0 : layer == 1 ? o1 : layer == 2 ? o2 : o3;
    int kk = i & 31, co = (i >> 5) & 255, cb = (i >> 13) & 7;
    o[i] = f2bf(w[co * 256 + cb * 32 + kk]);
}

__global__ void k_pack_c2dc1(const float* __restrict__ wc2, const float* __restrict__ wdc1,
                             ushort* __restrict__ oc2, ushort* __restrict__ odc1) {
    int g = blockIdx.x;
    int layer = g >> 12;
    int i = (g & 4095) * 256 + threadIdx.x;                      // 4*4*8*256*32 = 1048576
    int kk = i & 31, co = (i >> 5) & 255, cb = (i >> 13) & 7;
    int t = (i >> 16) & 3, cls = i >> 18;
    int a = t >> 1, b = t & 1, ci = cb * 32 + kk;
    if (layer == 0) {
        int ph = cls >> 1, pw = cls & 1;
        int kh = ph ? 2 * a : 2 * a + 1;
        int kw = pw ? 2 * b : 2 * b + 1;
        oc2[i] = f2bf(wc2[((co * 256 + ci) * 4 + kh) * 4 + kw]);
    } else {
        int py = cls >> 1, px = cls & 1;
        int kh0 = (py + 1) & 1, kw0 = (px + 1) & 1;
        odc1[i] = f2bf(wdc1[((ci * 256 + co) * 4 + kh0 + 2 * a) * 4 + kw0 + 2 * b]);
    }
}

__global__ void k_pack_c1f(const float* __restrict__ w, float* __restrict__ o) {
    int i = blockIdx.x * 256 + threadIdx.x;           // 48*256 = 12288
    int co = i & 255, k = i >> 8;
    int ci = k >> 4, kh = (k >> 2) & 3, kw = k & 3;
    o[k * 256 + co] = w[((co * 3 + ci) * 4 + kh) * 4 + kw];
}

// deconv2 MFMA weights: [tap(9)][cb(8)][oc(16)][k(32)] bf16
__global__ void k_pack_dc2m(const float* __restrict__ w, ushort* __restrict__ o) {
    int i = blockIdx.x * 256 + threadIdx.x;           // 9*8*16*32 = 36864
    int kk = i & 31, oc = (i >> 5) & 15, cb = (i >> 9) & 7, t = i >> 12;
    int dy = t / 3 - 1, dx = t % 3 - 1;
    int ci = cb * 32 + kk;
    float v = 0.f;
    if (oc < 12) {
        int cls = oc / 3, co = oc - cls * 3;
        int py = cls >> 1, px = cls & 1;
        int kh = 1 + py - 2 * dy, kw = 1 + px - 2 * dx;
        if ((unsigned)kh < 4u && (unsigned)kw < 4u)
            v = w[((ci * 3 + co) * 4 + kh) * 4 + kw];
    }
    o[i] = f2bf(v);
}

// VQ codebook prepack: apk [tile(16)][kstep(2)][lane(64)][8] bf16 ; en [256] fp32
__global__ void k_pack_vq(const float* __restrict__ cb, ushort* __restrict__ apk,
                          float* __restrict__ en) {
    if (blockIdx.x < 64) {
        int i = blockIdx.x * 256 + threadIdx.x;       // 0..16383
        int j = i & 7, lane = (i >> 3) & 63, s = (i >> 9) & 1, t = i >> 10;
        int code = t * 16 + (lane & 15);
        int dim = s * 32 + (lane >> 4) * 8 + j;
        apk[i] = f2bf(cb[code * 64 + dim]);
    } else {
        int code = threadIdx.x;
        float s = 0.f;
        for (int d = 0; d < 64; ++d) { float v = cb[code * 64 + d]; s += v * v; }
        en[code] = s;
    }
}

// ======================= conv1: 3->256 k4 s2, 128->64, LDS-staged =======================
__global__ __launch_bounds__(256) void k_conv1n(const float* __restrict__ x,
                                                const float* __restrict__ wt,   // [48][256] f32
                                                const float* __restrict__ bias,
                                                ushort* __restrict__ o) {       // NHWC64 bf16
    __shared__ float sx[12][132];
    int b = blockIdx.x;                  // 32n * 64h
    int h = b & 63, n = b >> 6;
    int tid = threadIdx.x;
    for (int c = tid; c < 12 * 128; c += 256) {
        int t = c >> 7, wi = c & 127;
        int ci = t >> 2, kh = t & 3;
        int hi = 2 * h - 1 + kh;
        float v = ((unsigned)hi < 128u) ? x[((long)n * 3 + ci) * 16384 + hi * 128 + wi] : 0.f;
        sx[t][wi + 1] = v;
    }
    if (tid < 24) { int t = tid >> 1; sx[t][(tid & 1) ? 129 : 0] = 0.f; }
    int co = tid;
    float wr[48];
#pragma unroll
    for (int k = 0; k < 48; ++k) wr[k] = wt[k * 256 + co];
    float bco = bias[co];
    __syncthreads();
    ushort* op = o + (((long)n * 64 + h) * 64) * 256 + co;
    for (int w = 0; w < 64; ++w) {
        float acc = bco;
#pragma unroll
        for (int t = 0; t < 12; ++t) {
            const float* xr = &sx[t][2 * w];
            acc += xr[0] * wr[t * 4] + xr[1] * wr[t * 4 + 1]
                 + xr[2] * wr[t * 4 + 2] + xr[3] * wr[t * 4 + 3];
        }
        op[w * 256] = f2bf(acc);
    }
}

// ======================= unified MFMA conv (2-wave blocks, pipelined) ===========
// MODE 0: 3x3 pad1 (9 taps), in 32x32 NHWC
// MODE 1: 1x1
// MODE 2: conv2 4x4 s2 (4 phases x 4 taps), in 64x64 NHWC
// MODE 3: deconv1 per-parity (4 taps), in 32x32 NHWC, out 64x64 NHWC
// Block: 128 threads = 2 waves. Block tile 64co x 128m. Wave tile 64co x 64m.
// Grid: [n][ (cls) ][coslab(4)][mblk(8)].
#define SXE(r, q, c) (((((r) << 2) + (q)) * 34 + (c)) << 3)

template <int MODE, bool HAS_BIAS, bool ADD_RES, bool WRITE_F32, bool WRITE_BF16, bool RELU_BF16>
__global__ __launch_bounds__(128, 2) void k_mconv(const ushort* __restrict__ xin,
                                                  const ushort* __restrict__ wpk,
                                                  const float* __restrict__ bias,
                                                  const float* __restrict__ res,
                                                  float* __restrict__ of32,
                                                  ushort* __restrict__ obf) {
    constexpr int NT = (MODE == 0) ? 9 : ((MODE == 1) ? 1 : 4);
    constexpr int NOUT = (MODE == 2) ? 32 : 8;
    constexpr int NR = (MODE == 1) ? 4 : 6;
    constexpr int NTA = (MODE == 0) ? 1 : NT;

    __shared__ __align__(16) ushort sX[6 * 4 * 34 * 8];   // 13056 B

    int tid = threadIdx.x;
    int lane = tid & 63, wv = tid >> 6;               // 2 waves
    int q = lane >> 4, l15 = lane & 15;
    int b = blockIdx.x;
    int mblk = b & 7, coslab = (b >> 3) & 3;
    int cls = (MODE == 3) ? ((b >> 5) & 3) : 0;
    int n = (MODE == 3) ? (b >> 7) : (b >> 5);
    int h0 = mblk * 4;

    if (tid < 48) {
        int r = tid / 8, rem = tid & 7, qq = rem >> 1, cc = (rem & 1) ? 33 : 0;
        uint4 z; z.x = z.y = z.z = z.w = 0;
        *(uint4*)&sX[SXE(r, qq, cc)] = z;
    }

    int qsel = tid & 3;
    int wst = (tid >> 2) & 31;

    int bbase[4];
#pragma unroll
    for (int bt = 0; bt < 4; ++bt) {
        int mloc = wv * 64 + bt * 16 + l15;           // 0..127
        int ro = mloc >> 5, col = mloc & 31;
        bbase[bt] = SXE(ro + 1, q, col + 1);
    }

    f32x4 acc[4][4];
#pragma unroll
    for (int at = 0; at < 4; ++at)
#pragma unroll
        for (int bt = 0; bt < 4; ++bt) acc[at][bt] = 0.f;

    uint4 sreg[NR];
    auto stage_load = [&](int it2) {
        int cb2 = (MODE == 2) ? (it2 >> 2) : it2;
        int ph2 = (MODE == 2) ? (it2 & 3) : 0;
        int ph_h2 = ph2 >> 1, ph_w2 = ph2 & 1;
#pragma unroll
        for (int r = 0; r < NR; ++r) {
            int rr = (MODE == 1) ? r + 1 : r;
            int hh = h0 + rr - 1;
            bool valid = (unsigned)hh < 32u;
            long off2;
            if (MODE == 2)
                off2 = (((long)n * 64 + 2 * hh + ph_h2) * 64 + (2 * wst + ph_w2)) * 256 + cb2 * 32 + qsel * 8;
            else
                off2 = (((long)n * 32 + hh) * 32 + wst) * 256 + cb2 * 32 + qsel * 8;
            uint4 v;
            if (valid) v = *(const uint4*)(xin + off2);
            else { v.x = 0; v.y = 0; v.z = 0; v.w = 0; }
            sreg[r] = v;
        }
    };
    stage_load(0);

    for (int it = 0; it < NOUT; ++it) {
        int cb = (MODE == 2) ? (it >> 2) : it;
        int ph = (MODE == 2) ? (it & 3) : 0;
        int ph_h = ph >> 1, ph_w = ph & 1;
        int clsi = (MODE == 2) ? ph : cls;
        const ushort* wb = wpk + ((((long)(clsi * NT)) * 8 + cb) * 256 + coslab * 64 + l15) * 32 + q * 8;

        // A-frag preload (independent of LDS; overlaps the barrier)
        bf16x8 afA[NTA][4];
        if (MODE == 0) {
#pragma unroll
            for (int at = 0; at < 4; ++at) afA[0][at] = *(const bf16x8*)(wb + at * 512);
        } else {
#pragma unroll
            for (int t = 0; t < NT; ++t)
#pragma unroll
                for (int at = 0; at < 4; ++at)
                    afA[t][at] = *(const bf16x8*)(wb + (long)t * 65536 + at * 512);
        }

        __syncthreads();                 // previous taps' LDS reads done
#pragma unroll
        for (int r = 0; r < NR; ++r) {
            int rr = (MODE == 1) ? r + 1 : r;
            *(uint4*)&sX[SXE(rr, qsel, wst + 1)] = sreg[r];
        }
        if (it + 1 < NOUT) stage_load(it + 1);   // prefetch next staging (loads in flight)
        __syncthreads();                 // staging visible

        if (MODE == 0) {
            bf16x8 afc[4];
#pragma unroll
            for (int at = 0; at < 4; ++at) afc[at] = afA[0][at];
#pragma unroll
            for (int t = 0; t < 9; ++t) {
                bf16x8 afn[4];
                if (t < 8) {
#pragma unroll
                    for (int at = 0; at < 4; ++at)
                        afn[at] = *(const bf16x8*)(wb + (long)(t + 1) * 65536 + at * 512);
                }
                int dy = t / 3 - 1, dx = t % 3 - 1;
                int doff = (dy * 136 + dx) * 8;
                bf16x8 bfr[4];
#pragma unroll
                for (int bt = 0; bt < 4; ++bt) bfr[bt] = *(const bf16x8*)&sX[bbase[bt] + doff];
#pragma unroll
                for (int at = 0; at < 4; ++at)
#pragma unroll
                    for (int bt = 0; bt < 4; ++bt)
                        acc[at][bt] = __builtin_amdgcn_mfma_f32_16x16x32_bf16(afc[at], bfr[bt],
                                                                              acc[at][bt], 0, 0, 0);
                if (t < 8) {
#pragma unroll
                    for (int at = 0; at < 4; ++at) afc[at] = afn[at];
                }
            }
        } else {
#pragma unroll
            for (int t = 0; t < NT; ++t) {
                int dy, dx;
                if (MODE == 1) { dy = 0; dx = 0; }
                else if (MODE == 2) { dy = (t >> 1) - ph_h; dx = (t & 1) - ph_w; }
                else { dy = (cls >> 1) - (t >> 1); dx = (cls & 1) - (t & 1); }
                int doff = (dy * 136 + dx) * 8;
                bf16x8 bfr[4];
#pragma unroll
                for (int bt = 0; bt < 4; ++bt) bfr[bt] = *(const bf16x8*)&sX[bbase[bt] + doff];
#pragma unroll
                for (int at = 0; at < 4; ++at)
#pragma unroll
                    for (int bt = 0; bt < 4; ++bt)
                        acc[at][bt] = __builtin_amdgcn_mfma_f32_16x16x32_bf16(afA[t][at], bfr[bt],
                                                                              acc[at][bt], 0, 0, 0);
            }
        }
    }

    // ---- epilogue ----
    int co_base = coslab * 64;
#pragma unroll
    for (int at = 0; at < 4; ++at) {
        int co_t = co_base + at * 16 + q * 4;
        float bv[4] = {0.f, 0.f, 0.f, 0.f};
        if (HAS_BIAS) {
            float4 b4 = *(const float4*)(bias + co_t);
            bv[0] = b4.x; bv[1] = b4.y; bv[2] = b4.z; bv[3] = b4.w;
        }
#pragma unroll
        for (int bt = 0; bt < 4; ++bt) {
            int m = mblk * 128 + wv * 64 + bt * 16 + l15;
            float v[4];
#pragma unroll
            for (int r = 0; r < 4; ++r) v[r] = acc[at][bt][r] + bv[r];
            if (ADD_RES) {
#pragma unroll
                for (int r = 0; r < 4; ++r)
                    v[r] += res[((long)(n * 256 + co_t + r)) * 1024 + m];
            }
            if (WRITE_F32) {
#pragma unroll
                for (int r = 0; r < 4; ++r)
                    of32[((long)(n * 256 + co_t + r)) * 1024 + m] = v[r];
            }
            if (WRITE_BF16) {
                unsigned p0, p1;
                {
                    float z0 = RELU_BF16 ? fmaxf(v[0], 0.f) : v[0];
                    float z1 = RELU_BF16 ? fmaxf(v[1], 0.f) : v[1];
                    float z2 = RELU_BF16 ? fmaxf(v[2], 0.f) : v[2];
                    float z3 = RELU_BF16 ? fmaxf(v[3], 0.f) : v[3];
                    p0 = (unsigned)f2bf(z0) | ((unsigned)f2bf(z1) << 16);
                    p1 = (unsigned)f2bf(z2) | ((unsigned)f2bf(z3) << 16);
                }
                long oaddr;
                if (MODE == 3) {
                    int oy = m >> 5, ox = m & 31;
                    int py = cls >> 1, px = cls & 1;
                    oaddr = (((long)n * 64 + 2 * oy + py) * 64 + 2 * ox + px) * 256 + co_t;
                } else {
                    oaddr = ((long)n * 1024 + m) * 256 + co_t;
                }
                uint2 pk; pk.x = p0; pk.y = p1;
                *(uint2*)(obf + oaddr) = pk;
            }
        }
    }
}

// ======================= VQ via MFMA =======================
__global__ __launch_bounds__(256) void k_vq2(const ushort* __restrict__ zb,
                                             const ushort* __restrict__ apk,  // [16][2][64][8]
                                             const float* __restrict__ en,    // [256]
                                             const float* __restrict__ cbf,   // [256][64] fp32
                                             float* __restrict__ vqf,         // fp32 NCHW
                                             ushort* __restrict__ vqb,        // bf16 NHWC relu
                                             float* __restrict__ loss) {
    __shared__ int sIdx[64];
    __shared__ float sLoss[64];
    int tid = threadIdx.x, lane = tid & 63, wv = tid >> 6;
    int q = lane >> 4, l15 = lane & 15;
    int r0 = blockIdx.x * 64;
    int R = r0 + wv * 16;

    const ushort* zp = zb + ((long)(R + l15)) * 64 + q * 8;
    bf16x8 b0 = *(const bf16x8*)zp;
    bf16x8 b1 = *(const bf16x8*)(zp + 32);

    float z2 = 0.f;
    {
        const unsigned* u0 = (const unsigned*)&b0;
        const unsigned* u1 = (const unsigned*)&b1;
#pragma unroll
        for (int i = 0; i < 4; ++i) {
            float a = bfl(u0[i]), bb = bfh(u0[i]);
            float c = bfl(u1[i]), d = bfh(u1[i]);
            z2 += a * a + bb * bb + c * c + d * d;
        }
    }

    float best = 3.4e38f;
    int bidx = 0;
#pragma unroll
    for (int t = 0; t < 16; ++t) {
        bf16x8 a0 = *(const bf16x8*)(apk + ((t * 2 + 0) * 64 + lane) * 8);
        bf16x8 a1 = *(const bf16x8*)(apk + ((t * 2 + 1) * 64 + lane) * 8);
        f32x4 acc = {0.f, 0.f, 0.f, 0.f};
        acc = __builtin_amdgcn_mfma_f32_16x16x32_bf16(a0, b0, acc, 0, 0, 0);
        acc = __builtin_amdgcn_mfma_f32_16x16x32_bf16(a1, b1, acc, 0, 0, 0);
        float4 e4 = *(const float4*)(en + t * 16 + q * 4);
        float sc[4] = {e4.x - 2.f * acc[0], e4.y - 2.f * acc[1],
                       e4.z - 2.f * acc[2], e4.w - 2.f * acc[3]};
#pragma unroll
        for (int r = 0; r < 4; ++r) {
            int code = t * 16 + q * 4 + r;
            if (sc[r] < best) { best = sc[r]; bidx = code; }
        }
    }
#pragma unroll
    for (int m = 16; m <= 32; m <<= 1) {
        float ob = __shfl_xor(best, m);
        int oi = __shfl_xor(bidx, m);
        if (ob < best || (ob == best && oi < bidx)) { best = ob; bidx = oi; }
        z2 += __shfl_xor(z2, m);
    }
    if (q == 0) {
        sIdx[wv * 16 + l15] = bidx;
        sLoss[wv * 16 + l15] = best + z2;
    }
    __syncthreads();

    if (wv == 0) {
        float l = sLoss[lane];
#pragma unroll
        for (int m = 1; m < 64; m <<= 1) l += __shfl_xor(l, m);
        if (lane == 0) atomicAdd(loss, l * (1.25f / 8388608.f));
    }

    int p0 = blockIdx.x * 16;
    int n = p0 >> 10, hw = p0 & 1023;
    long base = ((long)n * 256) * 1024 + hw;
#pragma unroll
    for (int k = 0; k < 16; ++k) {
        int i = k * 256 + tid;
        int pl = i & 15, gj = i >> 4;
        int g = gj >> 6, j = gj & 63;
        int idx = sIdx[pl * 4 + g];
        vqf[base + (long)gj * 1024 + pl] = cbf[idx * 64 + j];
    }
    unsigned* vb = (unsigned*)(vqb + (long)r0 * 64);
#pragma unroll
    for (int k = 0; k < 8; ++k) {
        int i = k * 256 + tid;
        int rl = i >> 5, jp = i & 31;
        int idx = sIdx[rl];
        float v0 = fmaxf(cbf[idx * 64 + 2 * jp], 0.f);
        float v1 = fmaxf(cbf[idx * 64 + 2 * jp + 1], 0.f);
        vb[i] = (unsigned)f2bf(v0) | ((unsigned)f2bf(v1) << 16);
    }
}

// ======================= deconv2 via MFMA: 256->3, 64->128, tanh (pipelined) ====
#define SDE(r, q, c) (((((r) << 2) + (q)) * 66 + (c)) << 3)

__global__ __launch_bounds__(256, 2) void k_deconv2m(const ushort* __restrict__ xin,
                                                     const ushort* __restrict__ wpk, // [9][8][16][32]
                                                     const float* __restrict__ bias,
                                                     float* __restrict__ o) {
    __shared__ __align__(16) ushort sX[6 * 4 * 66 * 8];   // 25344 B

    int tid = threadIdx.x, lane = tid & 63, wv = tid >> 6;
    int q = lane >> 4, l15 = lane & 15;
    int b = blockIdx.x;                   // 32n * 16mt = 512
    int mt = b & 15, n = b >> 4;
    int h0 = mt * 4;

    if (tid < 48) {
        int r = tid / 8, rem = tid & 7, qq = rem >> 1, cc = (rem & 1) ? 65 : 0;
        uint4 z; z.x = z.y = z.z = z.w = 0;
        *(uint4*)&sX[SDE(r, qq, cc)] = z;
    }

    int qsel = tid & 3, wst = (tid >> 2) & 63;

    int bbase[4];
#pragma unroll
    for (int bt = 0; bt < 4; ++bt) {
        int mloc = wv * 64 + bt * 16 + l15;       // 0..255
        int ro = mloc >> 6, col = mloc & 63;
        bbase[bt] = SDE(ro + 1, q, col + 1);
    }

    f32x4 acc[4];
#pragma unroll
    for (int bt = 0; bt < 4; ++bt) acc[bt] = 0.f;

    uint4 sreg[6];
    auto stage_load = [&](int cb2) {
#pragma unroll
        for (int r = 0; r < 6; ++r) {
            int hh = h0 + r - 1;
            uint4 v;
            if ((unsigned)hh < 64u)
                v = *(const uint4*)(xin + (((long)n * 64 + hh) * 64 + wst) * 256 + cb2 * 32 + qsel * 8);
            else { v.x = 0; v.y = 0; v.z = 0; v.w = 0; }
            sreg[r] = v;
        }
    };
    stage_load(0);

    for (int cb = 0; cb < 8; ++cb) {
        bf16x8 afA[9];
#pragma unroll
        for (int t = 0; t < 9; ++t)
            afA[t] = *(const bf16x8*)(wpk + (((t * 8 + cb) * 16 + l15) * 32 + q * 8));

        __syncthreads();
#pragma unroll
        for (int r = 0; r < 6; ++r)
            *(uint4*)&sX[SDE(r, qsel, wst + 1)] = sreg[r];
        if (cb < 7) stage_load(cb + 1);
        __syncthreads();

#pragma unroll
        for (int t = 0; t < 9; ++t) {
            int dy = t / 3 - 1, dx = t % 3 - 1;
            int doff = (dy * 4 * 66 + dx) * 8;
#pragma unroll
            for (int bt = 0; bt < 4; ++bt) {
                bf16x8 bf = *(const bf16x8*)&sX[bbase[bt] + doff];
                acc[bt] = __builtin_amdgcn_mfma_f32_16x16x32_bf16(afA[t], bf, acc[bt], 0, 0, 0);
            }
        }
    }

    if (q < 3) {
#pragma unroll
        for (int bt = 0; bt < 4; ++bt) {
            int mloc = wv * 64 + bt * 16 + l15;
            int u = h0 + (mloc >> 6), v = mloc & 63;
#pragma unroll
            for (int r = 0; r < 4; ++r) {
                int oc = q * 4 + r;
                int cls = oc / 3, cs = oc - cls * 3;
                int py = cls >> 1, px = cls & 1;
                o[(((long)n * 3 + cs) * 128 + 2 * u + py) * 128 + 2 * v + px] =
                    tanhf(acc[bt][r] + bias[cs]);
            }
        }
    }
}

// ======================= launcher =======================
extern "C" void kernel_launch(void* const* d_in, const int* in_sizes, int n_in,
                              void* d_out, int out_size, void* d_ws, size_t ws_size,
                              hipStream_t stream) {
    (void)in_sizes; (void)n_in; (void)out_size; (void)ws_size;
    const float* x        = (const float*)d_in[0];
    const float* enc_w1   = (const float*)d_in[1];
    const float* enc_b1   = (const float*)d_in[2];
    const float* enc_w2   = (const float*)d_in[3];
    const float* enc_b2   = (const float*)d_in[4];
    const float* er1_w3   = (const float*)d_in[5];
    const float* er1_w1   = (const float*)d_in[6];
    const float* er2_w3   = (const float*)d_in[7];
    const float* er2_w1   = (const float*)d_in[8];
    const float* codebook = (const float*)d_in[9];
    const float* dr1_w3   = (const float*)d_in[10];
    const float* dr1_w1   = (const float*)d_in[11];
    const float* dr2_w3   = (const float*)d_in[12];
    const float* dr2_w1   = (const float*)d_in[13];
    const float* dt1_w    = (const float*)d_in[14];
    const float* dt1_b    = (const float*)d_in[15];
    const float* dt2_w    = (const float*)d_in[16];
    const float* dt2_b    = (const float*)d_in[17];

    float* recon = (float*)d_out;
    float* loss  = recon + 1572864;

    char* ws = (char*)d_ws;
    size_t off = 0;
    auto alloc = [&](size_t bytes) { char* p = ws + off; off += (bytes + 255) & ~(size_t)255; return p; };
    ushort* N64  = (ushort*)alloc(67108864);   // [32,64,64,256] bf16
    float*  F0   = (float*)alloc(33554432);
    float*  F1   = (float*)alloc(33554432);
    ushort* B0   = (ushort*)alloc(16777216);
    ushort* B1   = (ushort*)alloc(16777216);
    ushort* B2   = (ushort*)alloc(16777216);
    ushort* wpk_c2   = (ushort*)alloc(2097152);
    ushort* wpk_dc1  = (ushort*)alloc(2097152);
    ushort* wpk_er13 = (ushort*)alloc(1179648);
    ushort* wpk_er23 = (ushort*)alloc(1179648);
    ushort* wpk_dr13 = (ushort*)alloc(1179648);
    ushort* wpk_dr23 = (ushort*)alloc(1179648);
    ushort* wpk_er11 = (ushort*)alloc(131072);
    ushort* wpk_er21 = (ushort*)alloc(131072);
    ushort* wpk_dr11 = (ushort*)alloc(131072);
    ushort* wpk_dr21 = (ushort*)alloc(131072);
    float*  wt_c1    = (float*)alloc(49152);
    ushort* w2pk     = (ushort*)alloc(73728);
    ushort* apk      = (ushort*)alloc(32768);
    float*  en       = (float*)alloc(1024);

    hipMemsetAsync(loss, 0, sizeof(float), stream);

    // weight packing
    k_pack_c1f<<<48, 256, 0, stream>>>(enc_w1, wt_c1);
    k_pack_c2dc1<<<8192, 256, 0, stream>>>(enc_w2, dt1_w, wpk_c2, wpk_dc1);
    k_pack_c3x4<<<9216, 256, 0, stream>>>(er1_w3, er2_w3, dr1_w3, dr2_w3,
                                          wpk_er13, wpk_er23, wpk_dr13, wpk_dr23);
    k_pack_c1x1x4<<<1024, 256, 0, stream>>>(er1_w1, er2_w1, dr1_w1, dr2_w1,
                                            wpk_er11, wpk_er21, wpk_dr11, wpk_dr21);
    k_pack_dc2m<<<144, 256, 0, stream>>>(dt2_w, w2pk);
    k_pack_vq<<<65, 256, 0, stream>>>(codebook, apk, en);

    // encoder
    k_conv1n<<<2048, 256, 0, stream>>>(x, wt_c1, enc_b1, N64);
    k_mconv<2, true, false, true, true, true><<<1024, 128, 0, stream>>>(N64, wpk_c2, enc_b2, nullptr, F0, B0);
    // er1
    k_mconv<0, false, false, false, true, true><<<1024, 128, 0, stream>>>(B0, wpk_er13, nullptr, nullptr, nullptr, B1);
    k_mconv<1, false, true, true, true, true><<<1024, 128, 0, stream>>>(B1, wpk_er11, nullptr, F0, F1, B0);
    // er2 (1x1 emits bf16 z NHWC for VQ, no relu)
    k_mconv<0, false, false, false, true, true><<<1024, 128, 0, stream>>>(B0, wpk_er23, nullptr, nullptr, nullptr, B1);
    k_mconv<1, false, true, false, true, false><<<1024, 128, 0, stream>>>(B1, wpk_er21, nullptr, F1, nullptr, B2);
    // VQ
    k_vq2<<<2048, 256, 0, stream>>>(B2, apk, en, codebook, F1, B0, loss);
    // dr1
    k_mconv<0, false, false, false, true, true><<<1024, 128, 0, stream>>>(B0, wpk_dr13, nullptr, nullptr, nullptr, B1);
    k_mconv<1, false, true, true, true, true><<<1024, 128, 0, stream>>>(B1, wpk_dr11, nullptr, F1, F0, B0);
    // dr2
    k_mconv<0, false, false, false, true, true><<<1024, 128, 0, stream>>>(B0, wpk_dr23, nullptr, nullptr, nullptr, B1);
    k_mconv<1, false, true, false, true, false><<<1024, 128, 0, stream>>>(B1, wpk_dr21, nullptr, F0, nullptr, B2);
    // deconv1
    k_mconv<3, true, false, false, true, false><<<4096, 128, 0, stream>>>(B2, wpk_dc1, dt1_b, nullptr, nullptr, N64);
    // deconv2 + tanh
    k_deconv2m<<<512, 256, 0, stream>>>(N64, w2pk, dt2_b, recon);
}